// Round 3
// baseline (108.082 us; speedup 1.0000x reference)
//
#include <hip/hip_runtime.h>

// ConvCRF forward, MI355X — round 18: f16 LDS halo + v_fma_mix_f32 tap loop.
// R17 post-mortem: f32 LDS halo was a pipe trade, not a win — bank conflicts
// 207K -> 2.16M (b128 at 400B stride = 4-way; b64 at 192B stride was free)
// and 2x LDS tap bytes (~8us/CU of LDS time, unhidden at 1 block/CU). The cvt
// savings went back to the LDS pipe.
// R18: revert sm halo to f16 (8B ds_read_b64, R15's conflict-free layout) and
// fold ALL f16->f32 converts into the accumulating FMA via v_fma_mix_f32
// (VOP3P, gfx9+): acc(f32) += f16half(sm_pair) * f16half(weight_pair).
//  - 12 fma_mix per tap, 0 cvt (R15: 12 fma + 4 sm-cvt + 2 weight-cvt;
//    R17: 12 fma + b128 LDS). Numerics bit-identical to R15 (exact f16->f32
//    promotion inside the FMA, f32 accumulate).
//  - bilateral weights consumed directly from packed f16 pair: batch0 = lo
//    half, batch1 = hi half (op_sel on src1).
// Carried from R17: poison-robust tag epochs (0x5EED<<16 | seq; no handshake,
// no zeroing pass), early sm0 publish at kernel top (sync hidden under the
// exp-heavy prologue), neighbor-only epoch sync, ring staging + interior
// self-write (raw f16 u64 copy, R15 style), diag fast path, LDS tap weights,
// O(19)/entry M prologue, relaxed agent-atomic f16 sm exchange.

typedef __attribute__((ext_vector_type(4))) _Float16 half4;
typedef __attribute__((ext_vector_type(2))) _Float16 half2f;

#define HH 160
#define WW 160
#define NPIX (HH*WW)
#define NC 19
#define NG 5
#define SPAN 3
#define TR 8
#define TC 16
#define NPXT 128
#define LR 14              // TR + 2*SPAN
#define LC 22              // TC + 2*SPAN
#define LCP 24             // halo row stride (8B units: float4 for rgb, half4 for sm)
#define HSTRIDE (LR*LCP)   // 336
#define NHALO (LR*LC)      // 308
#define NRING 180          // NHALO - 8*16 interior
#define NBLK 200
#define NTHR 640
#define EPSF 1e-20f

// epoch word encoding: hi16 = tag, lo16 = seq (it+1). Any hi16 != tag -> seq 0.
// Tag bytes differ (0x5E vs 0xED) so NO byte-uniform poison can alias it.
#define EPTAG   0x5EED0000u
#define EPMASK  0xFFFF0000u

// bar layout (u32 words): epoch[b] at word 32+b*32 (128B stride); word 0 unused
#define EPW(b) (32 + (b)*32)

#define SZ_A    30720
#define OFF_WB  SZ_A
#define SHM_SZ  (SZ_A + 25*128*8)   // 56,320

__device__ __forceinline__ float fast_rcp(float x) { return __builtin_amdgcn_rcpf(x); }

__device__ __forceinline__ float smx0(float q0, float q1) {
    const float m  = fmaxf(q0, q1);
    const float e0 = __expf(q0 - m);
    const float e1 = __expf(q1 - m);
    return e0 * fast_rcp(e0 + e1);
}

__device__ __forceinline__ unsigned ep_decode(unsigned w) {
    return ((w & EPMASK) == EPTAG) ? (w & 0xFFFFu) : 0u;
}

// acc(f32) += f16(lo/hi of pk) * w(f32)
__device__ __forceinline__ void mixf_lo(float& acc, unsigned pk, float w) {
    asm("v_fma_mix_f32 %0, %1, %2, %0 op_sel_hi:[1,0,0]"
        : "+v"(acc) : "v"(pk), "v"(w));
}
__device__ __forceinline__ void mixf_hi(float& acc, unsigned pk, float w) {
    asm("v_fma_mix_f32 %0, %1, %2, %0 op_sel:[1,0,0] op_sel_hi:[1,0,0]"
        : "+v"(acc) : "v"(pk), "v"(w));
}
// acc(f32) += f16(lo/hi of pk) * f16(lo/hi of wpk)
__device__ __forceinline__ void mix_ll(float& acc, unsigned pk, unsigned wpk) {
    asm("v_fma_mix_f32 %0, %1, %2, %0 op_sel_hi:[1,1,0]"
        : "+v"(acc) : "v"(pk), "v"(wpk));
}
__device__ __forceinline__ void mix_hl(float& acc, unsigned pk, unsigned wpk) {
    asm("v_fma_mix_f32 %0, %1, %2, %0 op_sel:[1,0,0] op_sel_hi:[1,1,0]"
        : "+v"(acc) : "v"(pk), "v"(wpk));
}
__device__ __forceinline__ void mix_lh(float& acc, unsigned pk, unsigned wpk) {
    asm("v_fma_mix_f32 %0, %1, %2, %0 op_sel:[0,1,0] op_sel_hi:[1,1,0]"
        : "+v"(acc) : "v"(pk), "v"(wpk));
}
__device__ __forceinline__ void mix_hh(float& acc, unsigned pk, unsigned wpk) {
    asm("v_fma_mix_f32 %0, %1, %2, %0 op_sel:[1,1,0] op_sel_hi:[1,1,0]"
        : "+v"(acc) : "v"(pk), "v"(wpk));
}

__global__ void __launch_bounds__(NTHR) crf_kernel(
        const float* __restrict__ u,
        const float* __restrict__ rgb,
        const float* __restrict__ sw,
        const float* __restrict__ bw,
        const float* __restrict__ compat,
        unsigned long long* __restrict__ gsmA,   // ping-pong sm0 fields (f16x4)
        unsigned long long* __restrict__ gsmB,
        unsigned* __restrict__ bar,
        float* __restrict__ out) {
    __shared__ __align__(16) char shm[SHM_SZ];
    __shared__ float Msh[960];                   // 20x48 rows [Ms|Mb|RS|pad]
    __shared__ float rowsum[NC];
    __shared__ int   diagflag;
    float4*   rgbL = (float4*)shm;               // prologue only (region A)
    half4*    smH  = (half4*)shm;                // per-iter sm0 halo, f16 (region A)
    float*    accF = (float*)shm;                // general-path epilogue (region A)
    unsigned* wbW  = (unsigned*)(shm + OFF_WB);
    const uint2* wbP = (const uint2*)(shm + OFF_WB);

    constexpr float WSPC[49] = {
        0.36787944f,0.48567179f,0.57375342f,0.60653066f,0.57375342f,0.48567179f,0.36787944f,
        0.48567179f,0.64118039f,0.75746513f,0.80073740f,0.75746513f,0.64118039f,0.48567179f,
        0.57375342f,0.75746513f,0.89483932f,0.94595947f,0.89483932f,0.75746513f,0.57375342f,
        0.60653066f,0.80073740f,0.94595947f,1.00000000f,0.94595947f,0.80073740f,0.60653066f,
        0.57375342f,0.75746513f,0.89483932f,0.94595947f,0.89483932f,0.75746513f,0.57375342f,
        0.48567179f,0.64118039f,0.75746513f,0.80073740f,0.75746513f,0.64118039f,0.48567179f,
        0.36787944f,0.48567179f,0.57375342f,0.60653066f,0.57375342f,0.48567179f,0.36787944f };

    const int tid = threadIdx.x;
    const int px  = tid & 127;
    const int g   = tid >> 7;
    const int r   = px >> 4, c = px & 15;
    const int ti0 = blockIdx.y * TR, tj0 = blockIdx.x * TC;
    const int gp  = (ti0 + r) * WW + (tj0 + c);
    const int ctr = (r + SPAN) * LCP + (c + SPAN);
    const int ku  = 4 * g;
    const int bid = blockIdx.y * 10 + blockIdx.x;    // grid (10, 20)

    // neighbor epochs to wait on (pad missing neighbors with own bid)
    int nb[8];
    {
        const int bx = blockIdx.x, by = blockIdx.y;
        int k = 0;
        #pragma unroll
        for (int dy2 = -1; dy2 <= 1; ++dy2)
            #pragma unroll
            for (int dx2 = -1; dx2 <= 1; ++dx2) {
                if (dx2 == 0 && dy2 == 0) continue;
                const int nx = bx + dx2, ny = by + dy2;
                nb[k++] = ((unsigned)nx < 10u && (unsigned)ny < 20u) ? (ny*10 + nx) : bid;
            }
    }

    if (tid == 0) diagflag = 1;

    // ---- earliest possible: own unaries -> sm0 -> publish (iteration 0) ----
    float uv0[4], uv1[4];
    #pragma unroll
    for (int i = 0; i < 4; ++i) {
        const int ch = 4*g + i;
        uv0[i] = (ch < NC) ? u[(size_t)gp * NC + ch] : 0.0f;
        uv1[i] = (ch < NC) ? u[((size_t)NPIX + gp) * NC + ch] : 0.0f;
    }
    half4 sh;
    #pragma unroll
    for (int i = 0; i < 4; ++i) sh[i] = (_Float16)smx0(uv0[i], uv1[i]);
    {
        unsigned long long u64; __builtin_memcpy(&u64, &sh, 8);
        __hip_atomic_store(&gsmA[g * NPIX + gp], u64,
                           __ATOMIC_RELAXED, __HIP_MEMORY_SCOPE_AGENT);
    }

    if (tid < NC) {
        float rs = 0.0f;
        for (int cb = 0; cb < NC; ++cb) rs += sw[tid*NC + cb] + bw[tid*NC + cb];
        rowsum[tid] = rs;
    }
    __syncthreads();             // drains ALL waves' sm0 publishes (vmcnt 0)
    if (tid == 0)                // epoch visible to neighbors during prologue
        __hip_atomic_store(&bar[EPW(bid)], EPTAG | 1u,
                           __ATOMIC_RELAXED, __HIP_MEMORY_SCOPE_AGENT);

    // ---- phase 0: M = [compat@sw | compat@bw | RS] into LDS, O(19)/entry ----
    for (int e = tid; e < 960; e += NTHR) {
        const int k = e / 48, cc2 = e % 48;
        float acc = 0.0f;
        if (k < NC) {
            if (cc2 < NC) {
                for (int j = 0; j < NC; ++j) acc += compat[k*NC + j] * sw[j*NC + cc2];
            } else if (cc2 >= 20 && cc2 < 20 + NC) {
                const int cb = cc2 - 20;
                for (int j = 0; j < NC; ++j) acc += compat[k*NC + j] * bw[j*NC + cb];
            } else if (cc2 == 40) {
                for (int j = 0; j < NC; ++j) acc += compat[k*NC + j] * rowsum[j];
            }
        }
        Msh[e] = acc;
        bool off = false;
        if (k < NC) {
            if (cc2 < NC && cc2 != k && acc != 0.0f) off = true;
            if (cc2 >= 20 && cc2 < 20 + NC && (cc2 - 20) != k && acc != 0.0f) off = true;
        }
        if (off) atomicAnd(&diagflag, 0);
    }
    __syncthreads();

    float dsv[4], dbv[4];
    #pragma unroll
    for (int i = 0; i < 4; ++i) {
        dsv[i] = Msh[(ku + i) * 48 + (ku + i)];
        dbv[i] = Msh[(ku + i) * 48 + 20 + (ku + i)];
    }
    const bool isdiag = (diagflag != 0);

    // ---- phase 1: rgb halo, both batches ----
    for (int e = tid; e < 2 * NHALO; e += NTHR) {
        const int bb = e / NHALO, pos = e % NHALO;
        const int hr = pos / LC, hc = pos % LC;
        const int yi = ti0 - SPAN + hr, xj = tj0 - SPAN + hc;
        float4 rv = make_float4(0.f, 0.f, 0.f, 0.f);
        if ((unsigned)yi < HH && (unsigned)xj < WW) {
            const float* p = rgb + ((size_t)(bb * NPIX) + yi * WW + xj) * 3;
            rv = make_float4(p[0]*(1.f/160.f), p[1]*(1.f/160.f), p[2]*(1.f/160.f), 1.f);
        }
        rgbL[(bb ? HSTRIDE : 0) + hr * LCP + hc] = rv;
    }
    __syncthreads();

    // ---- phase 2a: bilateral weights (tap-subset per group) -> LDS pairs ----
    {
        const float4 cv0 = rgbL[ctr];
        const float4 cv1 = rgbL[HSTRIDE + ctr];
        const int tapb = g * 10;
        const int ntap = (g == 4) ? 9 : 10;
        for (int i = 0; i < ntap; ++i) {
            const int t = tapb + i;
            const int dx = t / 7 - SPAN, dy = t % 7 - SPAN;
            const int n = ctr + dx * LCP + dy;
            const float4 nv0 = rgbL[n];
            const float4 nv1 = rgbL[HSTRIDE + n];
            const float wsm = __expf(-(float)(dx*dx + dy*dy) * (1.f/18.f)) * nv0.w;
            const float dr0 = cv0.x-nv0.x, dg0 = cv0.y-nv0.y, db0 = cv0.z-nv0.z;
            const float dr1 = cv1.x-nv1.x, dg1 = cv1.y-nv1.y, db1 = cv1.z-nv1.z;
            const float wb0 = wsm * __expf(-0.5f*(dr0*dr0+dg0*dg0+db0*db0));
            const float wb1 = wsm * __expf(-0.5f*(dr1*dr1+dg1*dg1+db1*db1));
            half2f hw = {(_Float16)wb0, (_Float16)wb1};
            unsigned uw; __builtin_memcpy(&uw, &hw, 4);
            wbW[(t >> 1) * 256 + px * 2 + (t & 1)] = uw;
        }
        if (g == 4) wbW[24 * 256 + px * 2 + 1] = 0u;
    }
    __syncthreads();

    // ---- phase 2b: per-pixel inverse norms ----
    float snI, bnI0, bnI1;
    {
        float sn = 0.f, bn0 = 0.f, bn1 = 0.f;
        #pragma unroll
        for (int t = 0; t < 49; ++t) {
            const unsigned uw = wbW[(t >> 1) * 256 + px * 2 + (t & 1)];
            half2f hw; __builtin_memcpy(&hw, &uw, 4);
            bn0 += (float)hw.x; bn1 += (float)hw.y;
            const int dx = t / 7 - SPAN, dy = t % 7 - SPAN;
            const int yi = ti0 + r + dx, xj = tj0 + c + dy;
            sn += (((unsigned)yi < HH) && ((unsigned)xj < WW)) ? WSPC[t] : 0.0f;
        }
        snI  = fast_rcp(sn + EPSF);
        bnI0 = fast_rcp(bn0 + EPSF);
        bnI1 = fast_rcp(bn1 + EPSF);
    }

    for (int it = 0; it < 5; ++it) {
        // drain tail publishes of this iteration (vmcnt 0) + all waves past
        // previous LDS reads -> region A reusable
        __syncthreads();

        // interior self-write from registers (overlaps tid0's poll)
        smH[g * HSTRIDE + ctr] = sh;

        // ---- neighbor-only epoch sync (tag-encoded, poison-robust) ----
        if (tid == 0) {
            const unsigned seq = (unsigned)(it + 1);
            if (it > 0)
                __hip_atomic_store(&bar[EPW(bid)], EPTAG | seq,
                                   __ATOMIC_RELAXED, __HIP_MEMORY_SCOPE_AGENT);
            unsigned mn;
            do {
                mn = 0xFFFFu;
                #pragma unroll
                for (int k = 0; k < 8; ++k) {
                    const unsigned w = __hip_atomic_load(&bar[EPW(nb[k])],
                                                         __ATOMIC_RELAXED, __HIP_MEMORY_SCOPE_AGENT);
                    const unsigned e = ep_decode(w);
                    mn = (e < mn) ? e : mn;
                }
                if (mn < seq) __builtin_amdgcn_s_sleep(1);
            } while (mn < seq);
        }
        __syncthreads();

        // ---- stage: ring from gsm (raw f16 u64 copy) ----
        const unsigned long long* gsrc = ((it & 1) ? gsmB : gsmA);
        #pragma unroll
        for (int k2 = 0; k2 < 2; ++k2) {
            const int e = tid + NTHR * k2;
            if (e < NG * NRING) {
                const int sg = e / NRING, re = e - sg * NRING;
                int hr, hc;
                if (re < 66)        { hr = re / 22;          hc = re % 22; }
                else if (re < 132)  { const int t2 = re - 66;  hr = 11 + t2 / 22; hc = t2 % 22; }
                else                { const int t2 = re - 132; hr = 3 + t2 / 6;
                                      const int s = t2 % 6;    hc = (s < 3) ? s : s + 16; }
                const int yi = ti0 - SPAN + hr, xj = tj0 - SPAN + hc;
                half4 hv = (half4)(_Float16)0.0f;
                if ((unsigned)yi < HH && (unsigned)xj < WW) {
                    const unsigned long long raw =
                        __hip_atomic_load(&gsrc[sg * NPIX + yi * WW + xj],
                                          __ATOMIC_RELAXED, __HIP_MEMORY_SCOPE_AGENT);
                    __builtin_memcpy(&hv, &raw, 8);
                }
                smH[sg * HSTRIDE + hr * LCP + hc] = hv;
            }
        }
        __syncthreads();

        // ---- 49 taps, all converts folded into v_fma_mix_f32 ----
        float sA[4] = {0,0,0,0}, b0[4] = {0,0,0,0}, b1[4] = {0,0,0,0};
        const half4* pl = smH + g * HSTRIDE;

        #define TAPMIX(T, WPK) do {                                          \
            const int dx_ = (T) / 7 - SPAN, dy_ = (T) % 7 - SPAN;            \
            uint2 hv_; __builtin_memcpy(&hv_, &pl[ctr + dx_*LCP + dy_], 8);  \
            mixf_lo(sA[0], hv_.x, WSPC[T]); mixf_hi(sA[1], hv_.x, WSPC[T]);  \
            mixf_lo(sA[2], hv_.y, WSPC[T]); mixf_hi(sA[3], hv_.y, WSPC[T]);  \
            mix_ll(b0[0], hv_.x, WPK);      mix_hl(b0[1], hv_.x, WPK);       \
            mix_ll(b0[2], hv_.y, WPK);      mix_hl(b0[3], hv_.y, WPK);       \
            mix_lh(b1[0], hv_.x, WPK);      mix_hh(b1[1], hv_.x, WPK);       \
            mix_lh(b1[2], hv_.y, WPK);      mix_hh(b1[3], hv_.y, WPK);       \
        } while (0)

        #pragma unroll
        for (int i = 0; i < 24; ++i) {
            const uint2 wp = wbP[i * 128 + px];
            TAPMIX(2*i,     wp.x);
            TAPMIX(2*i + 1, wp.y);
        }
        {   // tap 48
            const uint2 wp = wbP[24 * 128 + px];
            TAPMIX(48, wp.x);
        }
        #undef TAPMIX

        float q0v[4], q1v[4];
        if (isdiag) {
            #pragma unroll
            for (int i = 0; i < 4; ++i) {
                const float sAn = sA[i] * snI;
                const float b0n = b0[i] * bnI0;
                const float b1x = b1[i] * bnI1;
                q0v[i] = uv0[i] - dsv[i]*sAn - dbv[i]*b0n;
                q1v[i] = uv1[i] - (dsv[i] + dbv[i]) + dsv[i]*sAn + dbv[i]*b1x;
            }
        } else {
            __syncthreads();   // smH dead -> region A becomes accF
            #pragma unroll
            for (int i = 0; i < 4; ++i) {
                accF[(4*g + i) * NPXT + px]      = sA[i] * snI;
                accF[(20 + 4*g + i) * NPXT + px] = b0[i] * bnI0;
                accF[(40 + 4*g + i) * NPXT + px] = b1[i] * bnI1;
            }
            __syncthreads();
            float t1[4] = {0,0,0,0}, t2[4] = {0,0,0,0}, t3[4] = {0,0,0,0};
            #pragma unroll
            for (int cc = 0; cc < 20; ++cc) {
                const float sv  = accF[cc * NPXT + px];
                const float b0v = accF[(20 + cc) * NPXT + px];
                const float b1v = accF[(40 + cc) * NPXT + px];
                #pragma unroll
                for (int i = 0; i < 4; ++i) {
                    const float* mk = Msh + (ku + i) * 48;
                    t1[i] += mk[cc] * sv;
                    t2[i] += mk[20 + cc] * b0v;
                    t3[i] += mk[20 + cc] * b1v;
                }
            }
            #pragma unroll
            for (int i = 0; i < 4; ++i) {
                const float rs = Msh[(ku + i) * 48 + 40];
                q0v[i] = uv0[i] - t1[i] - t2[i];
                q1v[i] = uv1[i] - rs + t1[i] + t3[i];
            }
        }

        if (it == 4) {
            #pragma unroll
            for (int i = 0; i < 4; ++i) {
                const int ch = 4*g + i;
                if (ch < NC) {
                    out[(size_t)gp * NC + ch]          = q0v[i];
                    out[((size_t)NPIX + gp) * NC + ch] = q1v[i];
                }
            }
        } else {
            // sm for iteration it+1: f16 in regs (interior) + f16 publish (halo)
            #pragma unroll
            for (int i = 0; i < 4; ++i) sh[i] = (_Float16)smx0(q0v[i], q1v[i]);
            unsigned long long u64; __builtin_memcpy(&u64, &sh, 8);
            unsigned long long* gdst = (((it + 1) & 1) ? gsmB : gsmA);
            __hip_atomic_store(&gdst[g * NPIX + gp], u64,
                               __ATOMIC_RELAXED, __HIP_MEMORY_SCOPE_AGENT);
        }
    }
}

extern "C" void kernel_launch(void* const* d_in, const int* in_sizes, int n_in,
                              void* d_out, int out_size, void* d_ws, size_t ws_size,
                              hipStream_t stream) {
    const float* u      = (const float*)d_in[0];
    const float* rgb    = (const float*)d_in[1];
    const float* sw     = (const float*)d_in[2];
    const float* bw     = (const float*)d_in[3];
    const float* compat = (const float*)d_in[4];
    float* out = (float*)d_out;

    unsigned long long* gsmA = (unsigned long long*)d_ws;              // 1,024,000 B
    unsigned long long* gsmB = (unsigned long long*)((char*)d_ws + 1024000);
    unsigned* bar = (unsigned*)((char*)d_ws + 2048000);                // epochs (tag-encoded)

    crf_kernel<<<dim3(WW/TC, HH/TR, 1), dim3(NTHR), 0, stream>>>(
        u, rgb, sw, bw, compat, gsmA, gsmB, bar, out);
}

// Round 4
// 101.862 us; speedup vs baseline: 1.0611x; 1.0611x over previous
//
#include <hip/hip_runtime.h>

// ConvCRF forward, MI355X — round 19: R17 tap engine (f32 halo + v_pk_fma_f32)
//                                     + prologue TRANS/VALU cuts.
// R18 post-mortem: fma_mix halved LDS bytes but UNPACKED the FMAs (12 scalar
// fma_mix vs R17's 6 v_pk_fma_f32 per tap) -> 52us, worse than R17's 46.5.
// R17's f32-halo conflicts (2.16M) cost about what f16's cvts cost — a wash —
// but pk_fma is a 2x on the dominant VALU stream. R19 reverts the tap loop to
// R17 VERBATIM and attacks the prologue instead:
//  (1) phase2a: fold the spatial exponent into the batch exponent argument
//      (exp(a)*exp(b)=exp(a+b)): 2 exps/tap instead of 3 (-10 TRANS/thread).
//  (2) phase2b: per-group partial bilateral norms accumulated during 2a
//      (f16-rounded, matching tap weights), reduced over 5 groups — deletes
//      the 49-tap LDS re-read loop per pixel.
//  (3) spatial norm is separable: sn = R(row)*C(col), 12 selects vs 49 FMAs.
//  (4) rgb halo loads (1 elem/thread, 616<=640) issue AFTER the publish-drain
//      barrier but BEFORE the M-matrix compute — latency hides under M.
//      (Issuing before the barrier would be useless: __syncthreads' implicit
//      vmcnt(0) would drain the prefetch.)
// Carried from R17: poison-robust tag epochs, early sm0 publish, neighbor-only
// epoch sync, ring staging + f32 interior self-write, f32 LDS sm halo
// (LCP_F=25), diag fast path, LDS tap weights, O(19)/entry M prologue,
// relaxed agent-atomic f16 sm exchange.

typedef __attribute__((ext_vector_type(4))) _Float16 half4;
typedef __attribute__((ext_vector_type(2))) _Float16 half2f;
typedef __attribute__((ext_vector_type(4))) float float4v;

#define HH 160
#define WW 160
#define NPIX (HH*WW)
#define NC 19
#define NG 5
#define SPAN 3
#define TR 8
#define TC 16
#define NPXT 128
#define LR 14              // TR + 2*SPAN
#define LC 22              // TC + 2*SPAN
#define LCP 24             // rgb halo row stride (float4 units)
#define HSTRIDE (LR*LCP)   // 336 (rgb halo, float4 units)
#define LCP_F 25           // f32 sm halo row stride (float4 units)
#define HS_F (LR*LCP_F)    // 350
#define NHALO (LR*LC)      // 308
#define NRING 180          // NHALO - 8*16 interior
#define NBLK 200
#define NTHR 640
#define EPSF 1e-20f

// epoch word encoding: hi16 = tag, lo16 = seq (it+1). Any hi16 != tag -> seq 0.
// Tag bytes differ (0x5E vs 0xED) so NO byte-uniform poison can alias it.
#define EPTAG   0x5EED0000u
#define EPMASK  0xFFFF0000u

// bar layout (u32 words): epoch[b] at word 32+b*32 (128B stride); word 0 unused
#define EPW(b) (32 + (b)*32)

#define SZ_A    30720
#define OFF_WB  SZ_A
#define PN_OFF  20480               // partial norms: 5*128 float2 = 5120B (in region A)
#define SHM_SZ  (SZ_A + 25*128*8)   // 56,320

__device__ __forceinline__ float fast_rcp(float x) { return __builtin_amdgcn_rcpf(x); }

__device__ __forceinline__ float smx0(float q0, float q1) {
    const float m  = fmaxf(q0, q1);
    const float e0 = __expf(q0 - m);
    const float e1 = __expf(q1 - m);
    return e0 * fast_rcp(e0 + e1);
}

__device__ __forceinline__ unsigned ep_decode(unsigned w) {
    return ((w & EPMASK) == EPTAG) ? (w & 0xFFFFu) : 0u;
}

__global__ void __launch_bounds__(NTHR) crf_kernel(
        const float* __restrict__ u,
        const float* __restrict__ rgb,
        const float* __restrict__ sw,
        const float* __restrict__ bw,
        const float* __restrict__ compat,
        unsigned long long* __restrict__ gsmA,   // ping-pong sm0 fields (f16x4)
        unsigned long long* __restrict__ gsmB,
        unsigned* __restrict__ bar,
        float* __restrict__ out) {
    __shared__ __align__(16) char shm[SHM_SZ];
    __shared__ float Msh[960];                   // 20x48 rows [Ms|Mb|RS|pad]
    __shared__ float rowsum[NC];
    __shared__ int   diagflag;
    float4*   rgbL = (float4*)shm;               // prologue only (region A)
    float4v*  smF  = (float4v*)shm;              // per-iter sm0 halo, f32 (region A)
    float*    accF = (float*)shm;                // general-path epilogue (region A)
    unsigned* wbW  = (unsigned*)(shm + OFF_WB);
    const uint2* wbP = (const uint2*)(shm + OFF_WB);

    constexpr float WSPC[49] = {
        0.36787944f,0.48567179f,0.57375342f,0.60653066f,0.57375342f,0.48567179f,0.36787944f,
        0.48567179f,0.64118039f,0.75746513f,0.80073740f,0.75746513f,0.64118039f,0.48567179f,
        0.57375342f,0.75746513f,0.89483932f,0.94595947f,0.89483932f,0.75746513f,0.57375342f,
        0.60653066f,0.80073740f,0.94595947f,1.00000000f,0.94595947f,0.80073740f,0.60653066f,
        0.57375342f,0.75746513f,0.89483932f,0.94595947f,0.89483932f,0.75746513f,0.57375342f,
        0.48567179f,0.64118039f,0.75746513f,0.80073740f,0.75746513f,0.64118039f,0.48567179f,
        0.36787944f,0.48567179f,0.57375342f,0.60653066f,0.57375342f,0.48567179f,0.36787944f };

    const int tid = threadIdx.x;
    const int px  = tid & 127;
    const int g   = tid >> 7;
    const int r   = px >> 4, c = px & 15;
    const int ti0 = blockIdx.y * TR, tj0 = blockIdx.x * TC;
    const int gp  = (ti0 + r) * WW + (tj0 + c);
    const int ctr  = (r + SPAN) * LCP   + (c + SPAN);   // rgb halo center
    const int ctrF = (r + SPAN) * LCP_F + (c + SPAN);   // f32 sm halo center
    const int ku  = 4 * g;
    const int bid = blockIdx.y * 10 + blockIdx.x;    // grid (10, 20)

    // neighbor epochs to wait on (pad missing neighbors with own bid)
    int nb[8];
    {
        const int bx = blockIdx.x, by = blockIdx.y;
        int k = 0;
        #pragma unroll
        for (int dy2 = -1; dy2 <= 1; ++dy2)
            #pragma unroll
            for (int dx2 = -1; dx2 <= 1; ++dx2) {
                if (dx2 == 0 && dy2 == 0) continue;
                const int nx = bx + dx2, ny = by + dy2;
                nb[k++] = ((unsigned)nx < 10u && (unsigned)ny < 20u) ? (ny*10 + nx) : bid;
            }
    }

    if (tid == 0) diagflag = 1;

    // ---- earliest possible: own unaries -> sm0 -> publish (iteration 0) ----
    float uv0[4], uv1[4];
    #pragma unroll
    for (int i = 0; i < 4; ++i) {
        const int ch = 4*g + i;
        uv0[i] = (ch < NC) ? u[(size_t)gp * NC + ch] : 0.0f;
        uv1[i] = (ch < NC) ? u[((size_t)NPIX + gp) * NC + ch] : 0.0f;
    }
    half4 sh;
    float smv[4];
    #pragma unroll
    for (int i = 0; i < 4; ++i) {
        smv[i] = smx0(uv0[i], uv1[i]);
        sh[i]  = (_Float16)smv[i];
    }
    {
        unsigned long long u64; __builtin_memcpy(&u64, &sh, 8);
        __hip_atomic_store(&gsmA[g * NPIX + gp], u64,
                           __ATOMIC_RELAXED, __HIP_MEMORY_SCOPE_AGENT);
    }

    if (tid < NC) {
        float rs = 0.0f;
        for (int cb = 0; cb < NC; ++cb) rs += sw[tid*NC + cb] + bw[tid*NC + cb];
        rowsum[tid] = rs;
    }
    __syncthreads();             // drains ALL waves' sm0 publishes (vmcnt 0)
    if (tid == 0)                // epoch visible to neighbors during prologue
        __hip_atomic_store(&bar[EPW(bid)], EPTAG | 1u,
                           __ATOMIC_RELAXED, __HIP_MEMORY_SCOPE_AGENT);

    // ---- rgb halo prefetch: 1 element/thread (616 <= 640), issued BEFORE the
    //      M compute so the global-load latency hides under it ----
    float4 rv;
    int rgb_idx = -1;
    if (tid < 2 * NHALO) {
        const int bb = tid / NHALO, pos = tid % NHALO;
        const int hr = pos / LC, hc = pos % LC;
        const int yi = ti0 - SPAN + hr, xj = tj0 - SPAN + hc;
        rv = make_float4(0.f, 0.f, 0.f, 0.f);
        if ((unsigned)yi < HH && (unsigned)xj < WW) {
            const float* p = rgb + ((size_t)(bb * NPIX) + yi * WW + xj) * 3;
            rv = make_float4(p[0]*(1.f/160.f), p[1]*(1.f/160.f), p[2]*(1.f/160.f), 1.f);
        }
        rgb_idx = (bb ? HSTRIDE : 0) + hr * LCP + hc;
    }

    // ---- phase 0: M = [compat@sw | compat@bw | RS] into LDS, O(19)/entry ----
    for (int e = tid; e < 960; e += NTHR) {
        const int k = e / 48, cc2 = e % 48;
        float acc = 0.0f;
        if (k < NC) {
            if (cc2 < NC) {
                for (int j = 0; j < NC; ++j) acc += compat[k*NC + j] * sw[j*NC + cc2];
            } else if (cc2 >= 20 && cc2 < 20 + NC) {
                const int cb = cc2 - 20;
                for (int j = 0; j < NC; ++j) acc += compat[k*NC + j] * bw[j*NC + cb];
            } else if (cc2 == 40) {
                for (int j = 0; j < NC; ++j) acc += compat[k*NC + j] * rowsum[j];
            }
        }
        Msh[e] = acc;
        bool off = false;
        if (k < NC) {
            if (cc2 < NC && cc2 != k && acc != 0.0f) off = true;
            if (cc2 >= 20 && cc2 < 20 + NC && (cc2 - 20) != k && acc != 0.0f) off = true;
        }
        if (off) atomicAnd(&diagflag, 0);
    }

    // ---- phase 1: rgb halo writeback (waits on the prefetch here) ----
    if (rgb_idx >= 0) rgbL[rgb_idx] = rv;
    __syncthreads();             // covers Msh + rgbL

    float dsv[4], dbv[4];
    #pragma unroll
    for (int i = 0; i < 4; ++i) {
        dsv[i] = Msh[(ku + i) * 48 + (ku + i)];
        dbv[i] = Msh[(ku + i) * 48 + 20 + (ku + i)];
    }
    const bool isdiag = (diagflag != 0);

    // ---- phase 2a: bilateral weights (tap-subset per group) -> LDS pairs,
    //      spatial exponent folded into the batch exponent (2 exps/tap),
    //      f16-rounded partial norms accumulated on the fly ----
    {
        const float4 cv0 = rgbL[ctr];
        const float4 cv1 = rgbL[HSTRIDE + ctr];
        const int tapb = g * 10;
        const int ntap = (g == 4) ? 9 : 10;
        float pn0 = 0.f, pn1 = 0.f;
        for (int i = 0; i < ntap; ++i) {
            const int t = tapb + i;
            const int dx = t / 7 - SPAN, dy = t % 7 - SPAN;
            const int n = ctr + dx * LCP + dy;
            const float4 nv0 = rgbL[n];
            const float4 nv1 = rgbL[HSTRIDE + n];
            const float spc = (float)(dx*dx + dy*dy) * (-1.f/18.f);
            const float dr0 = cv0.x-nv0.x, dg0 = cv0.y-nv0.y, db0 = cv0.z-nv0.z;
            const float dr1 = cv1.x-nv1.x, dg1 = cv1.y-nv1.y, db1 = cv1.z-nv1.z;
            const float d0 = dr0*dr0 + dg0*dg0 + db0*db0;
            const float d1 = dr1*dr1 + dg1*dg1 + db1*db1;
            const float wb0 = nv0.w * __expf(fmaf(d0, -0.5f, spc));
            const float wb1 = nv0.w * __expf(fmaf(d1, -0.5f, spc));
            half2f hw = {(_Float16)wb0, (_Float16)wb1};
            unsigned uw; __builtin_memcpy(&uw, &hw, 4);
            wbW[(t >> 1) * 256 + px * 2 + (t & 1)] = uw;
            pn0 += (float)hw.x; pn1 += (float)hw.y;
        }
        if (g == 4) wbW[24 * 256 + px * 2 + 1] = 0u;
        *(float2*)(shm + PN_OFF + (g * 128 + px) * 8) = make_float2(pn0, pn1);
    }
    __syncthreads();

    // ---- phase 2b: inverse norms — 5-term partial reduce + separable sn ----
    float snI, bnI0, bnI1;
    {
        float bn0 = 0.f, bn1 = 0.f;
        #pragma unroll
        for (int g2 = 0; g2 < 5; ++g2) {
            const float2 p = *(const float2*)(shm + PN_OFF + (g2 * 128 + px) * 8);
            bn0 += p.x; bn1 += p.y;
        }
        const int rg = ti0 + r, cg = tj0 + c;
        float Rr = 5.70645506f, Cc = 5.70645506f;
        Rr -= (rg < 3   ? 0.60653066f : 0.f) + (rg < 2   ? 0.80073740f : 0.f)
            + (rg < 1   ? 0.94595947f : 0.f) + (rg > 156 ? 0.60653066f : 0.f)
            + (rg > 157 ? 0.80073740f : 0.f) + (rg > 158 ? 0.94595947f : 0.f);
        Cc -= (cg < 3   ? 0.60653066f : 0.f) + (cg < 2   ? 0.80073740f : 0.f)
            + (cg < 1   ? 0.94595947f : 0.f) + (cg > 156 ? 0.60653066f : 0.f)
            + (cg > 157 ? 0.80073740f : 0.f) + (cg > 158 ? 0.94595947f : 0.f);
        snI  = fast_rcp(Rr * Cc + EPSF);
        bnI0 = fast_rcp(bn0 + EPSF);
        bnI1 = fast_rcp(bn1 + EPSF);
    }

    for (int it = 0; it < 5; ++it) {
        // drain tail publishes of this iteration (vmcnt 0) + all waves past
        // previous LDS reads (incl. 2b's partial reads) -> region A reusable
        __syncthreads();

        // interior self-write from f32 registers (overlaps tid0's poll)
        {
            const float4v sv = {smv[0], smv[1], smv[2], smv[3]};
            smF[g * HS_F + ctrF] = sv;
        }

        // ---- neighbor-only epoch sync (tag-encoded, poison-robust) ----
        if (tid == 0) {
            const unsigned seq = (unsigned)(it + 1);
            if (it > 0)
                __hip_atomic_store(&bar[EPW(bid)], EPTAG | seq,
                                   __ATOMIC_RELAXED, __HIP_MEMORY_SCOPE_AGENT);
            unsigned mn;
            do {
                mn = 0xFFFFu;
                #pragma unroll
                for (int k = 0; k < 8; ++k) {
                    const unsigned w = __hip_atomic_load(&bar[EPW(nb[k])],
                                                         __ATOMIC_RELAXED, __HIP_MEMORY_SCOPE_AGENT);
                    const unsigned e = ep_decode(w);
                    mn = (e < mn) ? e : mn;
                }
                if (mn < seq) __builtin_amdgcn_s_sleep(1);
            } while (mn < seq);
        }
        __syncthreads();

        // ---- stage: ring from gsm (f16 -> f32 once) ----
        const unsigned long long* gsrc = ((it & 1) ? gsmB : gsmA);
        #pragma unroll
        for (int k2 = 0; k2 < 2; ++k2) {
            const int e = tid + NTHR * k2;
            if (e < NG * NRING) {
                const int sg = e / NRING, re = e - sg * NRING;
                int hr, hc;
                if (re < 66)        { hr = re / 22;          hc = re % 22; }
                else if (re < 132)  { const int t2 = re - 66;  hr = 11 + t2 / 22; hc = t2 % 22; }
                else                { const int t2 = re - 132; hr = 3 + t2 / 6;
                                      const int s = t2 % 6;    hc = (s < 3) ? s : s + 16; }
                const int yi = ti0 - SPAN + hr, xj = tj0 - SPAN + hc;
                float4v fv = (float4v)0.0f;
                if ((unsigned)yi < HH && (unsigned)xj < WW) {
                    const unsigned long long raw =
                        __hip_atomic_load(&gsrc[sg * NPIX + yi * WW + xj],
                                          __ATOMIC_RELAXED, __HIP_MEMORY_SCOPE_AGENT);
                    half4 hv; __builtin_memcpy(&hv, &raw, 8);
                    fv = (float4v){(float)hv[0], (float)hv[1], (float)hv[2], (float)hv[3]};
                }
                smF[sg * HS_F + hr * LCP_F + hc] = fv;
            }
        }
        __syncthreads();

        // ---- 49 taps as 24 pairs + 1 (f32 LDS reads -> v_pk_fma_f32) ----
        float4v sAv = (float4v)0.0f, b0a = (float4v)0.0f, b1a = (float4v)0.0f;
        const float4v* pl = smF + g * HS_F;
        #pragma unroll
        for (int i = 0; i < 24; ++i) {
            const uint2 wp = wbP[i * 128 + px];
            #pragma unroll
            for (int s = 0; s < 2; ++s) {
                const int t = 2*i + s;
                const int dx = t / 7 - SPAN, dy = t % 7 - SPAN;
                half2f hw; __builtin_memcpy(&hw, s ? &wp.y : &wp.x, 4);
                const float w0 = (float)hw.x, w1 = (float)hw.y;
                const float4v f = pl[ctrF + dx*LCP_F + dy];
                sAv += WSPC[t] * f;
                b0a += w0 * f;
                b1a += w1 * f;
            }
        }
        {   // tap 48
            const uint2 wp = wbP[24 * 128 + px];
            half2f hw; __builtin_memcpy(&hw, &wp.x, 4);
            const float w0 = (float)hw.x, w1 = (float)hw.y;
            const float4v f = pl[ctrF + SPAN*LCP_F + SPAN];
            sAv += WSPC[48] * f;
            b0a += w0 * f;
            b1a += w1 * f;
        }

        float q0v[4], q1v[4];
        if (isdiag) {
            #pragma unroll
            for (int i = 0; i < 4; ++i) {
                const float sAn = sAv[i] * snI;
                const float b0n = b0a[i] * bnI0;
                const float b1x = b1a[i] * bnI1;
                q0v[i] = uv0[i] - dsv[i]*sAn - dbv[i]*b0n;
                q1v[i] = uv1[i] - (dsv[i] + dbv[i]) + dsv[i]*sAn + dbv[i]*b1x;
            }
        } else {
            __syncthreads();   // smF dead -> region A becomes accF
            #pragma unroll
            for (int i = 0; i < 4; ++i) {
                accF[(4*g + i) * NPXT + px]      = sAv[i] * snI;
                accF[(20 + 4*g + i) * NPXT + px] = b0a[i] * bnI0;
                accF[(40 + 4*g + i) * NPXT + px] = b1a[i] * bnI1;
            }
            __syncthreads();
            float t1[4] = {0,0,0,0}, t2[4] = {0,0,0,0}, t3[4] = {0,0,0,0};
            #pragma unroll
            for (int cc = 0; cc < 20; ++cc) {
                const float sv  = accF[cc * NPXT + px];
                const float b0v = accF[(20 + cc) * NPXT + px];
                const float b1v = accF[(40 + cc) * NPXT + px];
                #pragma unroll
                for (int i = 0; i < 4; ++i) {
                    const float* mk = Msh + (ku + i) * 48;
                    t1[i] += mk[cc] * sv;
                    t2[i] += mk[20 + cc] * b0v;
                    t3[i] += mk[20 + cc] * b1v;
                }
            }
            #pragma unroll
            for (int i = 0; i < 4; ++i) {
                const float rs = Msh[(ku + i) * 48 + 40];
                q0v[i] = uv0[i] - t1[i] - t2[i];
                q1v[i] = uv1[i] - rs + t1[i] + t3[i];
            }
        }

        if (it == 4) {
            #pragma unroll
            for (int i = 0; i < 4; ++i) {
                const int ch = 4*g + i;
                if (ch < NC) {
                    out[(size_t)gp * NC + ch]          = q0v[i];
                    out[((size_t)NPIX + gp) * NC + ch] = q1v[i];
                }
            }
        } else {
            // sm for iteration it+1: f32 in regs (interior) + f16 publish (halo)
            #pragma unroll
            for (int i = 0; i < 4; ++i) {
                smv[i] = smx0(q0v[i], q1v[i]);
                sh[i]  = (_Float16)smv[i];
            }
            unsigned long long u64; __builtin_memcpy(&u64, &sh, 8);
            unsigned long long* gdst = (((it + 1) & 1) ? gsmB : gsmA);
            __hip_atomic_store(&gdst[g * NPIX + gp], u64,
                               __ATOMIC_RELAXED, __HIP_MEMORY_SCOPE_AGENT);
        }
    }
}

extern "C" void kernel_launch(void* const* d_in, const int* in_sizes, int n_in,
                              void* d_out, int out_size, void* d_ws, size_t ws_size,
                              hipStream_t stream) {
    const float* u      = (const float*)d_in[0];
    const float* rgb    = (const float*)d_in[1];
    const float* sw     = (const float*)d_in[2];
    const float* bw     = (const float*)d_in[3];
    const float* compat = (const float*)d_in[4];
    float* out = (float*)d_out;

    unsigned long long* gsmA = (unsigned long long*)d_ws;              // 1,024,000 B
    unsigned long long* gsmB = (unsigned long long*)((char*)d_ws + 1024000);
    unsigned* bar = (unsigned*)((char*)d_ws + 2048000);                // epochs (tag-encoded)

    crf_kernel<<<dim3(WW/TC, HH/TR, 1), dim3(NTHR), 0, stream>>>(
        u, rgb, sw, bw, compat, gsmA, gsmB, bar, out);
}

// Round 5
// 100.165 us; speedup vs baseline: 1.0790x; 1.0169x over previous
//
#include <hip/hip_runtime.h>

// ConvCRF forward, MI355X — round 20: conflict-free f32 halo (two float2 planes).
// R19 post-mortem: in-loop LDS pipe is dominant (~3.35us/iter of ~7), and 27%
// of it is bank-conflict stall (2.15M cycles). ds_read_b128's 32-lane phase
// covers 128 words = 4x all banks -> inherent >=4-way conflict at ANY stride.
// The R15 f16 layout (b64 @ 192B row stride) covers each bank exactly 2x per
// phase = free (m136). R20 keeps the f32 halo + v_pk_fma_f32 tap engine but
// splits channels into TWO float2 planes (ch01, ch23), each 8B/elem at 24-elem
// (192B) row stride: per tap 2x ds_read_b64 (same bytes as one b128), proven
// conflict-free geometry, same 6 pk_fma via two float2v accumulators/stream.
// Everything else byte-identical to R19: poison-robust tag epochs, early sm0
// publish, neighbor-only epoch sync, rgb-halo prefetch under M-compute, folded
// spatial exponent (2 exps/tap), partial bilateral norms, separable spatial
// norm, ring staging + f32 interior self-write, diag fast path, LDS tap
// weights, O(19)/entry M prologue, relaxed agent-atomic f16 sm exchange.

typedef __attribute__((ext_vector_type(4))) _Float16 half4;
typedef __attribute__((ext_vector_type(2))) _Float16 half2f;
typedef __attribute__((ext_vector_type(2))) float float2v;

#define HH 160
#define WW 160
#define NPIX (HH*WW)
#define NC 19
#define NG 5
#define SPAN 3
#define TR 8
#define TC 16
#define NPXT 128
#define LR 14              // TR + 2*SPAN
#define LC 22              // TC + 2*SPAN
#define LCP 24             // halo row stride (elements: float4 rgb / float2 sm)
#define HSTRIDE (LR*LCP)   // 336
#define NHALO (LR*LC)      // 308
#define NRING 180          // NHALO - 8*16 interior
#define NBLK 200
#define NTHR 640
#define EPSF 1e-20f

// epoch word encoding: hi16 = tag, lo16 = seq (it+1). Any hi16 != tag -> seq 0.
// Tag bytes differ (0x5E vs 0xED) so NO byte-uniform poison can alias it.
#define EPTAG   0x5EED0000u
#define EPMASK  0xFFFF0000u

// bar layout (u32 words): epoch[b] at word 32+b*32 (128B stride); word 0 unused
#define EPW(b) (32 + (b)*32)

#define SZ_A    30720
#define OFF_23  13440               // second float2 plane (ch2,ch3), 5*336*8 B each
#define OFF_WB  SZ_A
#define PN_OFF  27000               // partial norms: 5*128 float2 = 5120B (27000..32120 < wbW? no!)
#undef  PN_OFF
#define PN_OFF  26880               // right after plane 2 (26880..32000 > 30720 X) -> use 2a-safe slot
// NOTE: partial norms live only between phase 2a (write) and 2b (read); rgbL
// occupies 0..10752 then. Place PN at 10752 (inside region A, after rgbL).
#undef  PN_OFF
#define PN_OFF  10752
#define SHM_SZ  (SZ_A + 25*128*8)   // 56,320

__device__ __forceinline__ float fast_rcp(float x) { return __builtin_amdgcn_rcpf(x); }

__device__ __forceinline__ float smx0(float q0, float q1) {
    const float m  = fmaxf(q0, q1);
    const float e0 = __expf(q0 - m);
    const float e1 = __expf(q1 - m);
    return e0 * fast_rcp(e0 + e1);
}

__device__ __forceinline__ unsigned ep_decode(unsigned w) {
    return ((w & EPMASK) == EPTAG) ? (w & 0xFFFFu) : 0u;
}

__global__ void __launch_bounds__(NTHR) crf_kernel(
        const float* __restrict__ u,
        const float* __restrict__ rgb,
        const float* __restrict__ sw,
        const float* __restrict__ bw,
        const float* __restrict__ compat,
        unsigned long long* __restrict__ gsmA,   // ping-pong sm0 fields (f16x4)
        unsigned long long* __restrict__ gsmB,
        unsigned* __restrict__ bar,
        float* __restrict__ out) {
    __shared__ __align__(16) char shm[SHM_SZ];
    __shared__ float Msh[960];                   // 20x48 rows [Ms|Mb|RS|pad]
    __shared__ float rowsum[NC];
    __shared__ int   diagflag;
    float4*   rgbL = (float4*)shm;               // prologue only (region A, 0..10752)
    float2v*  smF01 = (float2v*)shm;             // sm halo ch0,1 (region A, 0..13440)
    float2v*  smF23 = (float2v*)(shm + OFF_23);  // sm halo ch2,3 (13440..26880)
    float*    accF = (float*)shm;                // general-path epilogue (region A)
    unsigned* wbW  = (unsigned*)(shm + OFF_WB);
    const uint2* wbP = (const uint2*)(shm + OFF_WB);

    constexpr float WSPC[49] = {
        0.36787944f,0.48567179f,0.57375342f,0.60653066f,0.57375342f,0.48567179f,0.36787944f,
        0.48567179f,0.64118039f,0.75746513f,0.80073740f,0.75746513f,0.64118039f,0.48567179f,
        0.57375342f,0.75746513f,0.89483932f,0.94595947f,0.89483932f,0.75746513f,0.57375342f,
        0.60653066f,0.80073740f,0.94595947f,1.00000000f,0.94595947f,0.80073740f,0.60653066f,
        0.57375342f,0.75746513f,0.89483932f,0.94595947f,0.89483932f,0.75746513f,0.57375342f,
        0.48567179f,0.64118039f,0.75746513f,0.80073740f,0.75746513f,0.64118039f,0.48567179f,
        0.36787944f,0.48567179f,0.57375342f,0.60653066f,0.57375342f,0.48567179f,0.36787944f };

    const int tid = threadIdx.x;
    const int px  = tid & 127;
    const int g   = tid >> 7;
    const int r   = px >> 4, c = px & 15;
    const int ti0 = blockIdx.y * TR, tj0 = blockIdx.x * TC;
    const int gp  = (ti0 + r) * WW + (tj0 + c);
    const int ctr = (r + SPAN) * LCP + (c + SPAN);   // shared halo center (rgb & sm planes)
    const int ku  = 4 * g;
    const int bid = blockIdx.y * 10 + blockIdx.x;    // grid (10, 20)

    // neighbor epochs to wait on (pad missing neighbors with own bid)
    int nb[8];
    {
        const int bx = blockIdx.x, by = blockIdx.y;
        int k = 0;
        #pragma unroll
        for (int dy2 = -1; dy2 <= 1; ++dy2)
            #pragma unroll
            for (int dx2 = -1; dx2 <= 1; ++dx2) {
                if (dx2 == 0 && dy2 == 0) continue;
                const int nx = bx + dx2, ny = by + dy2;
                nb[k++] = ((unsigned)nx < 10u && (unsigned)ny < 20u) ? (ny*10 + nx) : bid;
            }
    }

    if (tid == 0) diagflag = 1;

    // ---- earliest possible: own unaries -> sm0 -> publish (iteration 0) ----
    float uv0[4], uv1[4];
    #pragma unroll
    for (int i = 0; i < 4; ++i) {
        const int ch = 4*g + i;
        uv0[i] = (ch < NC) ? u[(size_t)gp * NC + ch] : 0.0f;
        uv1[i] = (ch < NC) ? u[((size_t)NPIX + gp) * NC + ch] : 0.0f;
    }
    half4 sh;
    float smv[4];
    #pragma unroll
    for (int i = 0; i < 4; ++i) {
        smv[i] = smx0(uv0[i], uv1[i]);
        sh[i]  = (_Float16)smv[i];
    }
    {
        unsigned long long u64; __builtin_memcpy(&u64, &sh, 8);
        __hip_atomic_store(&gsmA[g * NPIX + gp], u64,
                           __ATOMIC_RELAXED, __HIP_MEMORY_SCOPE_AGENT);
    }

    if (tid < NC) {
        float rs = 0.0f;
        for (int cb = 0; cb < NC; ++cb) rs += sw[tid*NC + cb] + bw[tid*NC + cb];
        rowsum[tid] = rs;
    }
    __syncthreads();             // drains ALL waves' sm0 publishes (vmcnt 0)
    if (tid == 0)                // epoch visible to neighbors during prologue
        __hip_atomic_store(&bar[EPW(bid)], EPTAG | 1u,
                           __ATOMIC_RELAXED, __HIP_MEMORY_SCOPE_AGENT);

    // ---- rgb halo prefetch: 1 element/thread (616 <= 640), issued BEFORE the
    //      M compute so the global-load latency hides under it ----
    float4 rv;
    int rgb_idx = -1;
    if (tid < 2 * NHALO) {
        const int bb = tid / NHALO, pos = tid % NHALO;
        const int hr = pos / LC, hc = pos % LC;
        const int yi = ti0 - SPAN + hr, xj = tj0 - SPAN + hc;
        rv = make_float4(0.f, 0.f, 0.f, 0.f);
        if ((unsigned)yi < HH && (unsigned)xj < WW) {
            const float* p = rgb + ((size_t)(bb * NPIX) + yi * WW + xj) * 3;
            rv = make_float4(p[0]*(1.f/160.f), p[1]*(1.f/160.f), p[2]*(1.f/160.f), 1.f);
        }
        rgb_idx = (bb ? HSTRIDE : 0) + hr * LCP + hc;
    }

    // ---- phase 0: M = [compat@sw | compat@bw | RS] into LDS, O(19)/entry ----
    for (int e = tid; e < 960; e += NTHR) {
        const int k = e / 48, cc2 = e % 48;
        float acc = 0.0f;
        if (k < NC) {
            if (cc2 < NC) {
                for (int j = 0; j < NC; ++j) acc += compat[k*NC + j] * sw[j*NC + cc2];
            } else if (cc2 >= 20 && cc2 < 20 + NC) {
                const int cb = cc2 - 20;
                for (int j = 0; j < NC; ++j) acc += compat[k*NC + j] * bw[j*NC + cb];
            } else if (cc2 == 40) {
                for (int j = 0; j < NC; ++j) acc += compat[k*NC + j] * rowsum[j];
            }
        }
        Msh[e] = acc;
        bool off = false;
        if (k < NC) {
            if (cc2 < NC && cc2 != k && acc != 0.0f) off = true;
            if (cc2 >= 20 && cc2 < 20 + NC && (cc2 - 20) != k && acc != 0.0f) off = true;
        }
        if (off) atomicAnd(&diagflag, 0);
    }

    // ---- phase 1: rgb halo writeback (waits on the prefetch here) ----
    if (rgb_idx >= 0) rgbL[rgb_idx] = rv;
    __syncthreads();             // covers Msh + rgbL

    float dsv[4], dbv[4];
    #pragma unroll
    for (int i = 0; i < 4; ++i) {
        dsv[i] = Msh[(ku + i) * 48 + (ku + i)];
        dbv[i] = Msh[(ku + i) * 48 + 20 + (ku + i)];
    }
    const bool isdiag = (diagflag != 0);

    // ---- phase 2a: bilateral weights (tap-subset per group) -> LDS pairs,
    //      spatial exponent folded into the batch exponent (2 exps/tap),
    //      f16-rounded partial norms accumulated on the fly ----
    {
        const float4 cv0 = rgbL[ctr];
        const float4 cv1 = rgbL[HSTRIDE + ctr];
        const int tapb = g * 10;
        const int ntap = (g == 4) ? 9 : 10;
        float pn0 = 0.f, pn1 = 0.f;
        for (int i = 0; i < ntap; ++i) {
            const int t = tapb + i;
            const int dx = t / 7 - SPAN, dy = t % 7 - SPAN;
            const int n = ctr + dx * LCP + dy;
            const float4 nv0 = rgbL[n];
            const float4 nv1 = rgbL[HSTRIDE + n];
            const float spc = (float)(dx*dx + dy*dy) * (-1.f/18.f);
            const float dr0 = cv0.x-nv0.x, dg0 = cv0.y-nv0.y, db0 = cv0.z-nv0.z;
            const float dr1 = cv1.x-nv1.x, dg1 = cv1.y-nv1.y, db1 = cv1.z-nv1.z;
            const float d0 = dr0*dr0 + dg0*dg0 + db0*db0;
            const float d1 = dr1*dr1 + dg1*dg1 + db1*db1;
            const float wb0 = nv0.w * __expf(fmaf(d0, -0.5f, spc));
            const float wb1 = nv0.w * __expf(fmaf(d1, -0.5f, spc));
            half2f hw = {(_Float16)wb0, (_Float16)wb1};
            unsigned uw; __builtin_memcpy(&uw, &hw, 4);
            wbW[(t >> 1) * 256 + px * 2 + (t & 1)] = uw;
            pn0 += (float)hw.x; pn1 += (float)hw.y;
        }
        if (g == 4) wbW[24 * 256 + px * 2 + 1] = 0u;
        *(float2*)(shm + PN_OFF + (g * 128 + px) * 8) = make_float2(pn0, pn1);
    }
    __syncthreads();

    // ---- phase 2b: inverse norms — 5-term partial reduce + separable sn ----
    float snI, bnI0, bnI1;
    {
        float bn0 = 0.f, bn1 = 0.f;
        #pragma unroll
        for (int g2 = 0; g2 < 5; ++g2) {
            const float2 p = *(const float2*)(shm + PN_OFF + (g2 * 128 + px) * 8);
            bn0 += p.x; bn1 += p.y;
        }
        const int rg = ti0 + r, cg = tj0 + c;
        float Rr = 5.70645506f, Cc = 5.70645506f;
        Rr -= (rg < 3   ? 0.60653066f : 0.f) + (rg < 2   ? 0.80073740f : 0.f)
            + (rg < 1   ? 0.94595947f : 0.f) + (rg > 156 ? 0.60653066f : 0.f)
            + (rg > 157 ? 0.80073740f : 0.f) + (rg > 158 ? 0.94595947f : 0.f);
        Cc -= (cg < 3   ? 0.60653066f : 0.f) + (cg < 2   ? 0.80073740f : 0.f)
            + (cg < 1   ? 0.94595947f : 0.f) + (cg > 156 ? 0.60653066f : 0.f)
            + (cg > 157 ? 0.80073740f : 0.f) + (cg > 158 ? 0.94595947f : 0.f);
        snI  = fast_rcp(Rr * Cc + EPSF);
        bnI0 = fast_rcp(bn0 + EPSF);
        bnI1 = fast_rcp(bn1 + EPSF);
    }

    for (int it = 0; it < 5; ++it) {
        // drain tail publishes of this iteration (vmcnt 0) + all waves past
        // previous LDS reads (incl. 2b's partial reads) -> region A reusable
        __syncthreads();

        // interior self-write from f32 registers (overlaps tid0's poll)
        {
            const int o = g * HSTRIDE + ctr;
            smF01[o] = (float2v){smv[0], smv[1]};
            smF23[o] = (float2v){smv[2], smv[3]};
        }

        // ---- neighbor-only epoch sync (tag-encoded, poison-robust) ----
        if (tid == 0) {
            const unsigned seq = (unsigned)(it + 1);
            if (it > 0)
                __hip_atomic_store(&bar[EPW(bid)], EPTAG | seq,
                                   __ATOMIC_RELAXED, __HIP_MEMORY_SCOPE_AGENT);
            unsigned mn;
            do {
                mn = 0xFFFFu;
                #pragma unroll
                for (int k = 0; k < 8; ++k) {
                    const unsigned w = __hip_atomic_load(&bar[EPW(nb[k])],
                                                         __ATOMIC_RELAXED, __HIP_MEMORY_SCOPE_AGENT);
                    const unsigned e = ep_decode(w);
                    mn = (e < mn) ? e : mn;
                }
                if (mn < seq) __builtin_amdgcn_s_sleep(1);
            } while (mn < seq);
        }
        __syncthreads();

        // ---- stage: ring from gsm (f16 -> f32 once, split planes) ----
        const unsigned long long* gsrc = ((it & 1) ? gsmB : gsmA);
        #pragma unroll
        for (int k2 = 0; k2 < 2; ++k2) {
            const int e = tid + NTHR * k2;
            if (e < NG * NRING) {
                const int sg = e / NRING, re = e - sg * NRING;
                int hr, hc;
                if (re < 66)        { hr = re / 22;          hc = re % 22; }
                else if (re < 132)  { const int t2 = re - 66;  hr = 11 + t2 / 22; hc = t2 % 22; }
                else                { const int t2 = re - 132; hr = 3 + t2 / 6;
                                      const int s = t2 % 6;    hc = (s < 3) ? s : s + 16; }
                const int yi = ti0 - SPAN + hr, xj = tj0 - SPAN + hc;
                float2v f01 = (float2v)0.0f, f23 = (float2v)0.0f;
                if ((unsigned)yi < HH && (unsigned)xj < WW) {
                    const unsigned long long raw =
                        __hip_atomic_load(&gsrc[sg * NPIX + yi * WW + xj],
                                          __ATOMIC_RELAXED, __HIP_MEMORY_SCOPE_AGENT);
                    half4 hv; __builtin_memcpy(&hv, &raw, 8);
                    f01 = (float2v){(float)hv[0], (float)hv[1]};
                    f23 = (float2v){(float)hv[2], (float)hv[3]};
                }
                const int o = sg * HSTRIDE + hr * LCP + hc;
                smF01[o] = f01;
                smF23[o] = f23;
            }
        }
        __syncthreads();

        // ---- 49 taps as 24 pairs + 1: 2x ds_read_b64 (conflict-free) + pk_fma ----
        float2v sA0 = (float2v)0.0f, sA1 = (float2v)0.0f;
        float2v b0l = (float2v)0.0f, b0h = (float2v)0.0f;
        float2v b1l = (float2v)0.0f, b1h = (float2v)0.0f;
        const float2v* p01 = smF01 + g * HSTRIDE + ctr;
        const float2v* p23 = smF23 + g * HSTRIDE + ctr;
        #pragma unroll
        for (int i = 0; i < 24; ++i) {
            const uint2 wp = wbP[i * 128 + px];
            #pragma unroll
            for (int s = 0; s < 2; ++s) {
                const int t = 2*i + s;
                const int dx = t / 7 - SPAN, dy = t % 7 - SPAN;
                half2f hw; __builtin_memcpy(&hw, s ? &wp.y : &wp.x, 4);
                const float w0 = (float)hw.x, w1 = (float)hw.y;
                const float2v f0 = p01[dx*LCP + dy];
                const float2v f1 = p23[dx*LCP + dy];
                sA0 += WSPC[t] * f0;  sA1 += WSPC[t] * f1;
                b0l += w0 * f0;       b0h += w0 * f1;
                b1l += w1 * f0;       b1h += w1 * f1;
            }
        }
        {   // tap 48
            const uint2 wp = wbP[24 * 128 + px];
            half2f hw; __builtin_memcpy(&hw, &wp.x, 4);
            const float w0 = (float)hw.x, w1 = (float)hw.y;
            const float2v f0 = p01[SPAN*LCP + SPAN];
            const float2v f1 = p23[SPAN*LCP + SPAN];
            sA0 += WSPC[48] * f0;  sA1 += WSPC[48] * f1;
            b0l += w0 * f0;        b0h += w0 * f1;
            b1l += w1 * f0;        b1h += w1 * f1;
        }
        const float sAv[4] = {sA0.x, sA0.y, sA1.x, sA1.y};
        const float b0a[4] = {b0l.x, b0l.y, b0h.x, b0h.y};
        const float b1a[4] = {b1l.x, b1l.y, b1h.x, b1h.y};

        float q0v[4], q1v[4];
        if (isdiag) {
            #pragma unroll
            for (int i = 0; i < 4; ++i) {
                const float sAn = sAv[i] * snI;
                const float b0n = b0a[i] * bnI0;
                const float b1x = b1a[i] * bnI1;
                q0v[i] = uv0[i] - dsv[i]*sAn - dbv[i]*b0n;
                q1v[i] = uv1[i] - (dsv[i] + dbv[i]) + dsv[i]*sAn + dbv[i]*b1x;
            }
        } else {
            __syncthreads();   // sm planes dead -> region A becomes accF
            #pragma unroll
            for (int i = 0; i < 4; ++i) {
                accF[(4*g + i) * NPXT + px]      = sAv[i] * snI;
                accF[(20 + 4*g + i) * NPXT + px] = b0a[i] * bnI0;
                accF[(40 + 4*g + i) * NPXT + px] = b1a[i] * bnI1;
            }
            __syncthreads();
            float t1[4] = {0,0,0,0}, t2[4] = {0,0,0,0}, t3[4] = {0,0,0,0};
            #pragma unroll
            for (int cc = 0; cc < 20; ++cc) {
                const float sv  = accF[cc * NPXT + px];
                const float b0v = accF[(20 + cc) * NPXT + px];
                const float b1v = accF[(40 + cc) * NPXT + px];
                #pragma unroll
                for (int i = 0; i < 4; ++i) {
                    const float* mk = Msh + (ku + i) * 48;
                    t1[i] += mk[cc] * sv;
                    t2[i] += mk[20 + cc] * b0v;
                    t3[i] += mk[20 + cc] * b1v;
                }
            }
            #pragma unroll
            for (int i = 0; i < 4; ++i) {
                const float rs = Msh[(ku + i) * 48 + 40];
                q0v[i] = uv0[i] - t1[i] - t2[i];
                q1v[i] = uv1[i] - rs + t1[i] + t3[i];
            }
        }

        if (it == 4) {
            #pragma unroll
            for (int i = 0; i < 4; ++i) {
                const int ch = 4*g + i;
                if (ch < NC) {
                    out[(size_t)gp * NC + ch]          = q0v[i];
                    out[((size_t)NPIX + gp) * NC + ch] = q1v[i];
                }
            }
        } else {
            // sm for iteration it+1: f32 in regs (interior) + f16 publish (halo)
            #pragma unroll
            for (int i = 0; i < 4; ++i) {
                smv[i] = smx0(q0v[i], q1v[i]);
                sh[i]  = (_Float16)smv[i];
            }
            unsigned long long u64; __builtin_memcpy(&u64, &sh, 8);
            unsigned long long* gdst = (((it + 1) & 1) ? gsmB : gsmA);
            __hip_atomic_store(&gdst[g * NPIX + gp], u64,
                               __ATOMIC_RELAXED, __HIP_MEMORY_SCOPE_AGENT);
        }
    }
}

extern "C" void kernel_launch(void* const* d_in, const int* in_sizes, int n_in,
                              void* d_out, int out_size, void* d_ws, size_t ws_size,
                              hipStream_t stream) {
    const float* u      = (const float*)d_in[0];
    const float* rgb    = (const float*)d_in[1];
    const float* sw     = (const float*)d_in[2];
    const float* bw     = (const float*)d_in[3];
    const float* compat = (const float*)d_in[4];
    float* out = (float*)d_out;

    unsigned long long* gsmA = (unsigned long long*)d_ws;              // 1,024,000 B
    unsigned long long* gsmB = (unsigned long long*)((char*)d_ws + 1024000);
    unsigned* bar = (unsigned*)((char*)d_ws + 2048000);                // epochs (tag-encoded)

    crf_kernel<<<dim3(WW/TC, HH/TR, 1), dim3(NTHR), 0, stream>>>(
        u, rgb, sw, bw, compat, gsmA, gsmB, bar, out);
}

// Round 7
// 98.134 us; speedup vs baseline: 1.1014x; 1.0207x over previous
//
#include <hip/hip_runtime.h>

// ConvCRF forward, MI355X — round 22: R21 resubmit + bounded-spin watchdog.
// R21 died with "container failed twice" (no profile) — same signature as the
// R16 infra flake, but also what a deadlock-timeout looks like. Full re-audit
// found no hang: 256 blocks x 8 waves x ~48KB LDS = 3 blocks/CU capacity (all
// co-resident even on a partially-reserved chip), all barriers unconditional,
// all indices in bounds, epoch logic identical to the R17/R19/R20-proven one.
// R22 = R21 byte-identical EXCEPT a diagnostic watchdog in the epoch poll:
// bounded spin (~4M iterations ~ 0.2s) then proceed. Never triggers in normal
// operation; converts a would-be wedge into a completing kernel whose result
// discriminates flake (fast+passed) from real sync bug (failed/slow).
// R21 recap: grid (16,16)=256 blocks = one per CU (vs 200/256 busy before),
// 10x10 tiles, 512 thr (5 groups x 100 px, 12-lane idle tail). Per-CU in-loop
// work x0.78. Tap engine = R19's proven f32-b128-halo + v_pk_fma_f32 (b128
// with 4-way aliasing measured faster than split b64, R20). Carried: tag
// epochs, early sm0 publish, neighbor-only sync, rgb prefetch under M,
// 2-exp taps, partial bilateral norms, separable spatial norm, ring staging,
// diag fast path, LDS tap weights, O(19)/entry M, f16 agent-atomic exchange.

typedef __attribute__((ext_vector_type(4))) _Float16 half4;
typedef __attribute__((ext_vector_type(2))) _Float16 half2f;
typedef __attribute__((ext_vector_type(4))) float float4v;

#define HH 160
#define WW 160
#define NPIX (HH*WW)
#define NC 19
#define NG 5
#define SPAN 3
#define TR 10
#define TC 10
#define NPXT 100           // pixels per group
#define LR 16              // TR + 2*SPAN
#define LC 16              // TC + 2*SPAN
#define LCP 17             // halo row stride (float4 units, rgb & sm)
#define HSTRIDE (LR*LCP)   // 272
#define NHALO (LR*LC)      // 256
#define NRING 156          // NHALO - 10*10 interior
#define NBLK 256
#define NTHR 512
#define NACT 500           // active compute threads (5 groups x 100 px)
#define EPSF 1e-20f

// epoch word encoding: hi16 = tag, lo16 = seq (it+1). Any hi16 != tag -> seq 0.
// Tag bytes differ (0x5E vs 0xED) so NO byte-uniform poison can alias it.
#define EPTAG   0x5EED0000u
#define EPMASK  0xFFFF0000u

// bar layout (u32 words): epoch[b] at word 32+b*32 (128B stride); word 0 unused
#define EPW(b) (32 + (b)*32)

// region A (byte offsets in shm):
//   rgbL   : 0 .. 8704          (2 x 272 float4, prologue only)
//   PN     : 8704 .. 12704      (500 float2 partial norms, phase 2a->2b only)
//   smF    : 0 .. 21760         (5 x 272 float4, per-iter sm halo)
//   accF   : 0 .. 24000         (60 x 100 f32, dead-path epilogue)
#define SZ_A    24064
#define PN_OFF  8704
#define OFF_WB  SZ_A                // weights: 25 pairs x 200 words = 20000 B
#define SHM_SZ  (SZ_A + 20000)      // 44,064

__device__ __forceinline__ float fast_rcp(float x) { return __builtin_amdgcn_rcpf(x); }

__device__ __forceinline__ float smx0(float q0, float q1) {
    const float m  = fmaxf(q0, q1);
    const float e0 = __expf(q0 - m);
    const float e1 = __expf(q1 - m);
    return e0 * fast_rcp(e0 + e1);
}

__device__ __forceinline__ unsigned ep_decode(unsigned w) {
    return ((w & EPMASK) == EPTAG) ? (w & 0xFFFFu) : 0u;
}

__global__ void __launch_bounds__(NTHR) crf_kernel(
        const float* __restrict__ u,
        const float* __restrict__ rgb,
        const float* __restrict__ sw,
        const float* __restrict__ bw,
        const float* __restrict__ compat,
        unsigned long long* __restrict__ gsmA,   // ping-pong sm0 fields (f16x4)
        unsigned long long* __restrict__ gsmB,
        unsigned* __restrict__ bar,
        float* __restrict__ out) {
    __shared__ __align__(16) char shm[SHM_SZ];
    __shared__ float Msh[960];                   // 20x48 rows [Ms|Mb|RS|pad]
    __shared__ float rowsum[NC];
    __shared__ int   diagflag;
    float4*   rgbL = (float4*)shm;               // prologue only (region A)
    float4v*  smF  = (float4v*)shm;              // per-iter sm0 halo, f32 (region A)
    float*    accF = (float*)shm;                // general-path epilogue (region A)
    unsigned* wbW  = (unsigned*)(shm + OFF_WB);
    const uint2* wbP = (const uint2*)(shm + OFF_WB);

    constexpr float WSPC[49] = {
        0.36787944f,0.48567179f,0.57375342f,0.60653066f,0.57375342f,0.48567179f,0.36787944f,
        0.48567179f,0.64118039f,0.75746513f,0.80073740f,0.75746513f,0.64118039f,0.48567179f,
        0.57375342f,0.75746513f,0.89483932f,0.94595947f,0.89483932f,0.75746513f,0.57375342f,
        0.60653066f,0.80073740f,0.94595947f,1.00000000f,0.94595947f,0.80073740f,0.60653066f,
        0.57375342f,0.75746513f,0.89483932f,0.94595947f,0.89483932f,0.75746513f,0.57375342f,
        0.48567179f,0.64118039f,0.75746513f,0.80073740f,0.75746513f,0.64118039f,0.48567179f,
        0.36787944f,0.48567179f,0.57375342f,0.60653066f,0.57375342f,0.48567179f,0.36787944f };

    const int tid = threadIdx.x;
    const bool act = (tid < NACT);
    const int g   = tid / NPXT;                 // 0..4 (5 for idle tail, guarded)
    const int px  = tid - g * NPXT;             // 0..99
    const int r   = px / TC, c = px - r * TC;   // 10x10 tile coords
    const int ti0 = blockIdx.y * TR, tj0 = blockIdx.x * TC;
    const int gp  = (ti0 + r) * WW + (tj0 + c);
    const int ctr = (r + SPAN) * LCP + (c + SPAN);   // halo center (rgb & sm)
    const int ku  = 4 * g;
    const int bid = blockIdx.y * 16 + blockIdx.x;    // grid (16, 16)

    // neighbor epochs to wait on (pad missing neighbors with own bid)
    int nb[8];
    {
        const int bx = blockIdx.x, by = blockIdx.y;
        int k = 0;
        #pragma unroll
        for (int dy2 = -1; dy2 <= 1; ++dy2)
            #pragma unroll
            for (int dx2 = -1; dx2 <= 1; ++dx2) {
                if (dx2 == 0 && dy2 == 0) continue;
                const int nx = bx + dx2, ny = by + dy2;
                nb[k++] = ((unsigned)nx < 16u && (unsigned)ny < 16u) ? (ny*16 + nx) : bid;
            }
    }

    if (tid == 0) diagflag = 1;

    // ---- earliest possible: own unaries -> sm0 -> publish (iteration 0) ----
    float uv0[4], uv1[4];
    half4 sh;
    float smv[4];
    if (act) {
        #pragma unroll
        for (int i = 0; i < 4; ++i) {
            const int ch = 4*g + i;
            uv0[i] = (ch < NC) ? u[(size_t)gp * NC + ch] : 0.0f;
            uv1[i] = (ch < NC) ? u[((size_t)NPIX + gp) * NC + ch] : 0.0f;
        }
        #pragma unroll
        for (int i = 0; i < 4; ++i) {
            smv[i] = smx0(uv0[i], uv1[i]);
            sh[i]  = (_Float16)smv[i];
        }
        unsigned long long u64; __builtin_memcpy(&u64, &sh, 8);
        __hip_atomic_store(&gsmA[g * NPIX + gp], u64,
                           __ATOMIC_RELAXED, __HIP_MEMORY_SCOPE_AGENT);
    }

    if (tid < NC) {
        float rs = 0.0f;
        for (int cb = 0; cb < NC; ++cb) rs += sw[tid*NC + cb] + bw[tid*NC + cb];
        rowsum[tid] = rs;
    }
    __syncthreads();             // drains ALL waves' sm0 publishes (vmcnt 0)
    if (tid == 0)                // epoch visible to neighbors during prologue
        __hip_atomic_store(&bar[EPW(bid)], EPTAG | 1u,
                           __ATOMIC_RELAXED, __HIP_MEMORY_SCOPE_AGENT);

    // ---- rgb halo prefetch: exactly 1 element/thread (2*256 = 512 = NTHR),
    //      issued BEFORE the M compute so the load latency hides under it ----
    float4 rv;
    int rgb_idx;
    {
        const int bb = tid >> 8, pos = tid & 255;
        const int hr = pos >> 4, hc = pos & 15;
        const int yi = ti0 - SPAN + hr, xj = tj0 - SPAN + hc;
        rv = make_float4(0.f, 0.f, 0.f, 0.f);
        if ((unsigned)yi < HH && (unsigned)xj < WW) {
            const float* p = rgb + ((size_t)(bb * NPIX) + yi * WW + xj) * 3;
            rv = make_float4(p[0]*(1.f/160.f), p[1]*(1.f/160.f), p[2]*(1.f/160.f), 1.f);
        }
        rgb_idx = bb * HSTRIDE + hr * LCP + hc;
    }

    // ---- phase 0: M = [compat@sw | compat@bw | RS] into LDS, O(19)/entry ----
    for (int e = tid; e < 960; e += NTHR) {
        const int k = e / 48, cc2 = e % 48;
        float acc = 0.0f;
        if (k < NC) {
            if (cc2 < NC) {
                for (int j = 0; j < NC; ++j) acc += compat[k*NC + j] * sw[j*NC + cc2];
            } else if (cc2 >= 20 && cc2 < 20 + NC) {
                const int cb = cc2 - 20;
                for (int j = 0; j < NC; ++j) acc += compat[k*NC + j] * bw[j*NC + cb];
            } else if (cc2 == 40) {
                for (int j = 0; j < NC; ++j) acc += compat[k*NC + j] * rowsum[j];
            }
        }
        Msh[e] = acc;
        bool off = false;
        if (k < NC) {
            if (cc2 < NC && cc2 != k && acc != 0.0f) off = true;
            if (cc2 >= 20 && cc2 < 20 + NC && (cc2 - 20) != k && acc != 0.0f) off = true;
        }
        if (off) atomicAnd(&diagflag, 0);
    }

    // ---- phase 1: rgb halo writeback (waits on the prefetch here) ----
    rgbL[rgb_idx] = rv;
    __syncthreads();             // covers Msh + rgbL

    float dsv[4], dbv[4];
    #pragma unroll
    for (int i = 0; i < 4; ++i) {
        dsv[i] = Msh[(ku + i) * 48 + (ku + i)];
        dbv[i] = Msh[(ku + i) * 48 + 20 + (ku + i)];
    }
    const bool isdiag = (diagflag != 0);

    // ---- phase 2a: bilateral weights (tap-subset per group) -> LDS pairs,
    //      spatial exponent folded into the batch exponent (2 exps/tap),
    //      f16-rounded partial norms accumulated on the fly ----
    if (act) {
        const float4 cv0 = rgbL[ctr];
        const float4 cv1 = rgbL[HSTRIDE + ctr];
        const int tapb = g * 10;
        const int ntap = (g == 4) ? 9 : 10;
        float pn0 = 0.f, pn1 = 0.f;
        for (int i = 0; i < ntap; ++i) {
            const int t = tapb + i;
            const int dx = t / 7 - SPAN, dy = t % 7 - SPAN;
            const int n = ctr + dx * LCP + dy;
            const float4 nv0 = rgbL[n];
            const float4 nv1 = rgbL[HSTRIDE + n];
            const float spc = (float)(dx*dx + dy*dy) * (-1.f/18.f);
            const float dr0 = cv0.x-nv0.x, dg0 = cv0.y-nv0.y, db0 = cv0.z-nv0.z;
            const float dr1 = cv1.x-nv1.x, dg1 = cv1.y-nv1.y, db1 = cv1.z-nv1.z;
            const float d0 = dr0*dr0 + dg0*dg0 + db0*db0;
            const float d1 = dr1*dr1 + dg1*dg1 + db1*db1;
            const float wb0 = nv0.w * __expf(fmaf(d0, -0.5f, spc));
            const float wb1 = nv0.w * __expf(fmaf(d1, -0.5f, spc));
            half2f hw = {(_Float16)wb0, (_Float16)wb1};
            unsigned uw; __builtin_memcpy(&uw, &hw, 4);
            wbW[(t >> 1) * 200 + px * 2 + (t & 1)] = uw;
            pn0 += (float)hw.x; pn1 += (float)hw.y;
        }
        if (g == 4) wbW[24 * 200 + px * 2 + 1] = 0u;
        *(float2*)(shm + PN_OFF + (g * NPXT + px) * 8) = make_float2(pn0, pn1);
    }
    __syncthreads();

    // ---- phase 2b: inverse norms — 5-term partial reduce + separable sn ----
    float snI, bnI0, bnI1;
    if (act) {
        float bn0 = 0.f, bn1 = 0.f;
        #pragma unroll
        for (int g2 = 0; g2 < 5; ++g2) {
            const float2 p = *(const float2*)(shm + PN_OFF + (g2 * NPXT + px) * 8);
            bn0 += p.x; bn1 += p.y;
        }
        const int rg = ti0 + r, cg = tj0 + c;
        float Rr = 5.70645506f, Cc = 5.70645506f;
        Rr -= (rg < 3   ? 0.60653066f : 0.f) + (rg < 2   ? 0.80073740f : 0.f)
            + (rg < 1   ? 0.94595947f : 0.f) + (rg > 156 ? 0.60653066f : 0.f)
            + (rg > 157 ? 0.80073740f : 0.f) + (rg > 158 ? 0.94595947f : 0.f);
        Cc -= (cg < 3   ? 0.60653066f : 0.f) + (cg < 2   ? 0.80073740f : 0.f)
            + (cg < 1   ? 0.94595947f : 0.f) + (cg > 156 ? 0.60653066f : 0.f)
            + (cg > 157 ? 0.80073740f : 0.f) + (cg > 158 ? 0.94595947f : 0.f);
        snI  = fast_rcp(Rr * Cc + EPSF);
        bnI0 = fast_rcp(bn0 + EPSF);
        bnI1 = fast_rcp(bn1 + EPSF);
    }

    for (int it = 0; it < 5; ++it) {
        // drain tail publishes of this iteration (vmcnt 0) + all waves past
        // previous LDS reads (incl. 2b's partial reads) -> region A reusable
        __syncthreads();

        // interior self-write from f32 registers (overlaps tid0's poll)
        if (act) {
            const float4v sv = {smv[0], smv[1], smv[2], smv[3]};
            smF[g * HSTRIDE + ctr] = sv;
        }

        // ---- neighbor-only epoch sync (tag-encoded, poison-robust) ----
        // Bounded spin: never triggers when all blocks are live (polls exit in
        // ~us); converts a would-be deadlock into a completing-but-wrong run
        // so the bench result discriminates flake vs real sync bug.
        if (tid == 0) {
            const unsigned seq = (unsigned)(it + 1);
            if (it > 0)
                __hip_atomic_store(&bar[EPW(bid)], EPTAG | seq,
                                   __ATOMIC_RELAXED, __HIP_MEMORY_SCOPE_AGENT);
            unsigned mn;
            unsigned spins = 0;
            do {
                mn = 0xFFFFu;
                #pragma unroll
                for (int k = 0; k < 8; ++k) {
                    const unsigned w = __hip_atomic_load(&bar[EPW(nb[k])],
                                                         __ATOMIC_RELAXED, __HIP_MEMORY_SCOPE_AGENT);
                    const unsigned e = ep_decode(w);
                    mn = (e < mn) ? e : mn;
                }
                if (mn < seq) {
                    __builtin_amdgcn_s_sleep(1);
                    if (++spins > (1u << 22)) break;   // watchdog (~0.2s)
                }
            } while (mn < seq);
        }
        __syncthreads();

        // ---- stage: ring from gsm (f16 -> f32 once) ----
        const unsigned long long* gsrc = ((it & 1) ? gsmB : gsmA);
        #pragma unroll
        for (int k2 = 0; k2 < 2; ++k2) {
            const int e = tid + NTHR * k2;
            if (e < NG * NRING) {
                const int sg = e / NRING, re = e - sg * NRING;
                int hr, hc;
                if (re < 48)        { hr = re >> 4;               hc = re & 15; }
                else if (re < 96)   { hr = 13 + ((re - 48) >> 4); hc = (re - 48) & 15; }
                else                { const int t2 = re - 96; hr = 3 + t2 / 6;
                                      const int s = t2 % 6;   hc = (s < 3) ? s : s + 10; }
                const int yi = ti0 - SPAN + hr, xj = tj0 - SPAN + hc;
                float4v fv = (float4v)0.0f;
                if ((unsigned)yi < HH && (unsigned)xj < WW) {
                    const unsigned long long raw =
                        __hip_atomic_load(&gsrc[sg * NPIX + yi * WW + xj],
                                          __ATOMIC_RELAXED, __HIP_MEMORY_SCOPE_AGENT);
                    half4 hv; __builtin_memcpy(&hv, &raw, 8);
                    fv = (float4v){(float)hv[0], (float)hv[1], (float)hv[2], (float)hv[3]};
                }
                smF[sg * HSTRIDE + hr * LCP + hc] = fv;
            }
        }
        __syncthreads();

        // ---- 49 taps as 24 pairs + 1 (f32 b128 LDS reads -> v_pk_fma_f32) ----
        float4v sAv = (float4v)0.0f, b0a = (float4v)0.0f, b1a = (float4v)0.0f;
        if (act) {
            const float4v* pl = smF + g * HSTRIDE;
            #pragma unroll
            for (int i = 0; i < 24; ++i) {
                const uint2 wp = wbP[i * 100 + px];
                #pragma unroll
                for (int s = 0; s < 2; ++s) {
                    const int t = 2*i + s;
                    const int dx = t / 7 - SPAN, dy = t % 7 - SPAN;
                    half2f hw; __builtin_memcpy(&hw, s ? &wp.y : &wp.x, 4);
                    const float w0 = (float)hw.x, w1 = (float)hw.y;
                    const float4v f = pl[ctr + dx*LCP + dy];
                    sAv += WSPC[t] * f;
                    b0a += w0 * f;
                    b1a += w1 * f;
                }
            }
            {   // tap 48
                const uint2 wp = wbP[24 * 100 + px];
                half2f hw; __builtin_memcpy(&hw, &wp.x, 4);
                const float w0 = (float)hw.x, w1 = (float)hw.y;
                const float4v f = pl[ctr + SPAN*LCP + SPAN];
                sAv += WSPC[48] * f;
                b0a += w0 * f;
                b1a += w1 * f;
            }
        }

        float q0v[4], q1v[4];
        if (isdiag) {
            if (act) {
                #pragma unroll
                for (int i = 0; i < 4; ++i) {
                    const float sAn = sAv[i] * snI;
                    const float b0n = b0a[i] * bnI0;
                    const float b1x = b1a[i] * bnI1;
                    q0v[i] = uv0[i] - dsv[i]*sAn - dbv[i]*b0n;
                    q1v[i] = uv1[i] - (dsv[i] + dbv[i]) + dsv[i]*sAn + dbv[i]*b1x;
                }
            }
        } else {
            __syncthreads();   // smF dead -> region A becomes accF
            if (act) {
                #pragma unroll
                for (int i = 0; i < 4; ++i) {
                    accF[(4*g + i) * NPXT + px]      = sAv[i] * snI;
                    accF[(20 + 4*g + i) * NPXT + px] = b0a[i] * bnI0;
                    accF[(40 + 4*g + i) * NPXT + px] = b1a[i] * bnI1;
                }
            }
            __syncthreads();
            if (act) {
                float t1[4] = {0,0,0,0}, t2[4] = {0,0,0,0}, t3[4] = {0,0,0,0};
                #pragma unroll
                for (int cc = 0; cc < 20; ++cc) {
                    const float sv  = accF[cc * NPXT + px];
                    const float b0v = accF[(20 + cc) * NPXT + px];
                    const float b1v = accF[(40 + cc) * NPXT + px];
                    #pragma unroll
                    for (int i = 0; i < 4; ++i) {
                        const float* mk = Msh + (ku + i) * 48;
                        t1[i] += mk[cc] * sv;
                        t2[i] += mk[20 + cc] * b0v;
                        t3[i] += mk[20 + cc] * b1v;
                    }
                }
                #pragma unroll
                for (int i = 0; i < 4; ++i) {
                    const float rs = Msh[(ku + i) * 48 + 40];
                    q0v[i] = uv0[i] - t1[i] - t2[i];
                    q1v[i] = uv1[i] - rs + t1[i] + t3[i];
                }
            }
        }

        if (it == 4) {
            if (act) {
                #pragma unroll
                for (int i = 0; i < 4; ++i) {
                    const int ch = 4*g + i;
                    if (ch < NC) {
                        out[(size_t)gp * NC + ch]          = q0v[i];
                        out[((size_t)NPIX + gp) * NC + ch] = q1v[i];
                    }
                }
            }
        } else if (act) {
            // sm for iteration it+1: f32 in regs (interior) + f16 publish (halo)
            #pragma unroll
            for (int i = 0; i < 4; ++i) {
                smv[i] = smx0(q0v[i], q1v[i]);
                sh[i]  = (_Float16)smv[i];
            }
            unsigned long long u64; __builtin_memcpy(&u64, &sh, 8);
            unsigned long long* gdst = (((it + 1) & 1) ? gsmB : gsmA);
            __hip_atomic_store(&gdst[g * NPIX + gp], u64,
                               __ATOMIC_RELAXED, __HIP_MEMORY_SCOPE_AGENT);
        }
    }
}

extern "C" void kernel_launch(void* const* d_in, const int* in_sizes, int n_in,
                              void* d_out, int out_size, void* d_ws, size_t ws_size,
                              hipStream_t stream) {
    const float* u      = (const float*)d_in[0];
    const float* rgb    = (const float*)d_in[1];
    const float* sw     = (const float*)d_in[2];
    const float* bw     = (const float*)d_in[3];
    const float* compat = (const float*)d_in[4];
    float* out = (float*)d_out;

    unsigned long long* gsmA = (unsigned long long*)d_ws;              // 1,024,000 B
    unsigned long long* gsmB = (unsigned long long*)((char*)d_ws + 1024000);
    unsigned* bar = (unsigned*)((char*)d_ws + 2048000);                // epochs (tag-encoded)

    crf_kernel<<<dim3(WW/TC, HH/TR, 1), dim3(NTHR), 0, stream>>>(
        u, rgb, sw, bw, compat, gsmA, gsmB, bar, out);
}

// Round 8
// 95.826 us; speedup vs baseline: 1.1279x; 1.0241x over previous
//
#include <hip/hip_runtime.h>

// ConvCRF forward, MI355X — round 23: LCP 17->18 for exact-4x bank coverage.
// R22 post-mortem: 256-block re-tile paid (45.2->41.1us kernel) but bank
// conflicts ROSE 2.15M->3.98M (~6.5us/CU stall): with LCP=17, first-word bank
// = 4*((r+c) mod 8), whose 32-lane histogram over 10-wide rows is lumpy (5-6
// way on some banks). With LCP=18: bank = 4*((2r+c) mod 8), and m=(2r+c)
// increments +1 on BOTH c->c+1 and the (r,9)->(r+1,0) wrap, so m == lane mod 8
// -> every 32-lane phase covers each bank exactly 4x = the b128 minimum (R20
// proved b128+4way beats split b64). Only group-seam phases are slightly
// lumpy. smF 5x288 f4 = 23040B, rgb 2x288 f4 = 9216B; PN at 9216; all within
// the existing 24064B region A. Everything else byte-identical to R22 (incl.
// the zero-cost watchdog; R21's failure confirmed as infra flake).
// Note: harness dur_us includes its own 256MiB ws poison (~41us fill at 80%
// HBM, visible in the counter dump) — only the ~41us kernel is controllable.

typedef __attribute__((ext_vector_type(4))) _Float16 half4;
typedef __attribute__((ext_vector_type(2))) _Float16 half2f;
typedef __attribute__((ext_vector_type(4))) float float4v;

#define HH 160
#define WW 160
#define NPIX (HH*WW)
#define NC 19
#define NG 5
#define SPAN 3
#define TR 10
#define TC 10
#define NPXT 100           // pixels per group
#define LR 16              // TR + 2*SPAN
#define LC 16              // TC + 2*SPAN
#define LCP 18             // halo row stride (float4 units) — exact-4x banks
#define HSTRIDE (LR*LCP)   // 288
#define NHALO (LR*LC)      // 256
#define NRING 156          // NHALO - 10*10 interior
#define NBLK 256
#define NTHR 512
#define NACT 500           // active compute threads (5 groups x 100 px)
#define EPSF 1e-20f

// epoch word encoding: hi16 = tag, lo16 = seq (it+1). Any hi16 != tag -> seq 0.
// Tag bytes differ (0x5E vs 0xED) so NO byte-uniform poison can alias it.
#define EPTAG   0x5EED0000u
#define EPMASK  0xFFFF0000u

// bar layout (u32 words): epoch[b] at word 32+b*32 (128B stride); word 0 unused
#define EPW(b) (32 + (b)*32)

// region A (byte offsets in shm):
//   rgbL   : 0 .. 9216          (2 x 288 float4, prologue only)
//   PN     : 9216 .. 13216      (500 float2 partial norms, phase 2a->2b only)
//   smF    : 0 .. 23040         (5 x 288 float4, per-iter sm halo)
//   accF   : 0 .. 24000         (60 x 100 f32, dead-path epilogue)
#define SZ_A    24064
#define PN_OFF  9216
#define OFF_WB  SZ_A                // weights: 25 pairs x 200 words = 20000 B
#define SHM_SZ  (SZ_A + 20000)      // 44,064

__device__ __forceinline__ float fast_rcp(float x) { return __builtin_amdgcn_rcpf(x); }

__device__ __forceinline__ float smx0(float q0, float q1) {
    const float m  = fmaxf(q0, q1);
    const float e0 = __expf(q0 - m);
    const float e1 = __expf(q1 - m);
    return e0 * fast_rcp(e0 + e1);
}

__device__ __forceinline__ unsigned ep_decode(unsigned w) {
    return ((w & EPMASK) == EPTAG) ? (w & 0xFFFFu) : 0u;
}

__global__ void __launch_bounds__(NTHR) crf_kernel(
        const float* __restrict__ u,
        const float* __restrict__ rgb,
        const float* __restrict__ sw,
        const float* __restrict__ bw,
        const float* __restrict__ compat,
        unsigned long long* __restrict__ gsmA,   // ping-pong sm0 fields (f16x4)
        unsigned long long* __restrict__ gsmB,
        unsigned* __restrict__ bar,
        float* __restrict__ out) {
    __shared__ __align__(16) char shm[SHM_SZ];
    __shared__ float Msh[960];                   // 20x48 rows [Ms|Mb|RS|pad]
    __shared__ float rowsum[NC];
    __shared__ int   diagflag;
    float4*   rgbL = (float4*)shm;               // prologue only (region A)
    float4v*  smF  = (float4v*)shm;              // per-iter sm0 halo, f32 (region A)
    float*    accF = (float*)shm;                // general-path epilogue (region A)
    unsigned* wbW  = (unsigned*)(shm + OFF_WB);
    const uint2* wbP = (const uint2*)(shm + OFF_WB);

    constexpr float WSPC[49] = {
        0.36787944f,0.48567179f,0.57375342f,0.60653066f,0.57375342f,0.48567179f,0.36787944f,
        0.48567179f,0.64118039f,0.75746513f,0.80073740f,0.75746513f,0.64118039f,0.48567179f,
        0.57375342f,0.75746513f,0.89483932f,0.94595947f,0.89483932f,0.75746513f,0.57375342f,
        0.60653066f,0.80073740f,0.94595947f,1.00000000f,0.94595947f,0.80073740f,0.60653066f,
        0.57375342f,0.75746513f,0.89483932f,0.94595947f,0.89483932f,0.75746513f,0.57375342f,
        0.48567179f,0.64118039f,0.75746513f,0.80073740f,0.75746513f,0.64118039f,0.48567179f,
        0.36787944f,0.48567179f,0.57375342f,0.60653066f,0.57375342f,0.48567179f,0.36787944f };

    const int tid = threadIdx.x;
    const bool act = (tid < NACT);
    const int g   = tid / NPXT;                 // 0..4 (5 for idle tail, guarded)
    const int px  = tid - g * NPXT;             // 0..99
    const int r   = px / TC, c = px - r * TC;   // 10x10 tile coords
    const int ti0 = blockIdx.y * TR, tj0 = blockIdx.x * TC;
    const int gp  = (ti0 + r) * WW + (tj0 + c);
    const int ctr = (r + SPAN) * LCP + (c + SPAN);   // halo center (rgb & sm)
    const int ku  = 4 * g;
    const int bid = blockIdx.y * 16 + blockIdx.x;    // grid (16, 16)

    // neighbor epochs to wait on (pad missing neighbors with own bid)
    int nb[8];
    {
        const int bx = blockIdx.x, by = blockIdx.y;
        int k = 0;
        #pragma unroll
        for (int dy2 = -1; dy2 <= 1; ++dy2)
            #pragma unroll
            for (int dx2 = -1; dx2 <= 1; ++dx2) {
                if (dx2 == 0 && dy2 == 0) continue;
                const int nx = bx + dx2, ny = by + dy2;
                nb[k++] = ((unsigned)nx < 16u && (unsigned)ny < 16u) ? (ny*16 + nx) : bid;
            }
    }

    if (tid == 0) diagflag = 1;

    // ---- earliest possible: own unaries -> sm0 -> publish (iteration 0) ----
    float uv0[4], uv1[4];
    half4 sh;
    float smv[4];
    if (act) {
        #pragma unroll
        for (int i = 0; i < 4; ++i) {
            const int ch = 4*g + i;
            uv0[i] = (ch < NC) ? u[(size_t)gp * NC + ch] : 0.0f;
            uv1[i] = (ch < NC) ? u[((size_t)NPIX + gp) * NC + ch] : 0.0f;
        }
        #pragma unroll
        for (int i = 0; i < 4; ++i) {
            smv[i] = smx0(uv0[i], uv1[i]);
            sh[i]  = (_Float16)smv[i];
        }
        unsigned long long u64; __builtin_memcpy(&u64, &sh, 8);
        __hip_atomic_store(&gsmA[g * NPIX + gp], u64,
                           __ATOMIC_RELAXED, __HIP_MEMORY_SCOPE_AGENT);
    }

    if (tid < NC) {
        float rs = 0.0f;
        for (int cb = 0; cb < NC; ++cb) rs += sw[tid*NC + cb] + bw[tid*NC + cb];
        rowsum[tid] = rs;
    }
    __syncthreads();             // drains ALL waves' sm0 publishes (vmcnt 0)
    if (tid == 0)                // epoch visible to neighbors during prologue
        __hip_atomic_store(&bar[EPW(bid)], EPTAG | 1u,
                           __ATOMIC_RELAXED, __HIP_MEMORY_SCOPE_AGENT);

    // ---- rgb halo prefetch: exactly 1 element/thread (2*256 = 512 = NTHR),
    //      issued BEFORE the M compute so the load latency hides under it ----
    float4 rv;
    int rgb_idx;
    {
        const int bb = tid >> 8, pos = tid & 255;
        const int hr = pos >> 4, hc = pos & 15;
        const int yi = ti0 - SPAN + hr, xj = tj0 - SPAN + hc;
        rv = make_float4(0.f, 0.f, 0.f, 0.f);
        if ((unsigned)yi < HH && (unsigned)xj < WW) {
            const float* p = rgb + ((size_t)(bb * NPIX) + yi * WW + xj) * 3;
            rv = make_float4(p[0]*(1.f/160.f), p[1]*(1.f/160.f), p[2]*(1.f/160.f), 1.f);
        }
        rgb_idx = bb * HSTRIDE + hr * LCP + hc;
    }

    // ---- phase 0: M = [compat@sw | compat@bw | RS] into LDS, O(19)/entry ----
    for (int e = tid; e < 960; e += NTHR) {
        const int k = e / 48, cc2 = e % 48;
        float acc = 0.0f;
        if (k < NC) {
            if (cc2 < NC) {
                for (int j = 0; j < NC; ++j) acc += compat[k*NC + j] * sw[j*NC + cc2];
            } else if (cc2 >= 20 && cc2 < 20 + NC) {
                const int cb = cc2 - 20;
                for (int j = 0; j < NC; ++j) acc += compat[k*NC + j] * bw[j*NC + cb];
            } else if (cc2 == 40) {
                for (int j = 0; j < NC; ++j) acc += compat[k*NC + j] * rowsum[j];
            }
        }
        Msh[e] = acc;
        bool off = false;
        if (k < NC) {
            if (cc2 < NC && cc2 != k && acc != 0.0f) off = true;
            if (cc2 >= 20 && cc2 < 20 + NC && (cc2 - 20) != k && acc != 0.0f) off = true;
        }
        if (off) atomicAnd(&diagflag, 0);
    }

    // ---- phase 1: rgb halo writeback (waits on the prefetch here) ----
    rgbL[rgb_idx] = rv;
    __syncthreads();             // covers Msh + rgbL

    float dsv[4], dbv[4];
    #pragma unroll
    for (int i = 0; i < 4; ++i) {
        dsv[i] = Msh[(ku + i) * 48 + (ku + i)];
        dbv[i] = Msh[(ku + i) * 48 + 20 + (ku + i)];
    }
    const bool isdiag = (diagflag != 0);

    // ---- phase 2a: bilateral weights (tap-subset per group) -> LDS pairs,
    //      spatial exponent folded into the batch exponent (2 exps/tap),
    //      f16-rounded partial norms accumulated on the fly ----
    if (act) {
        const float4 cv0 = rgbL[ctr];
        const float4 cv1 = rgbL[HSTRIDE + ctr];
        const int tapb = g * 10;
        const int ntap = (g == 4) ? 9 : 10;
        float pn0 = 0.f, pn1 = 0.f;
        for (int i = 0; i < ntap; ++i) {
            const int t = tapb + i;
            const int dx = t / 7 - SPAN, dy = t % 7 - SPAN;
            const int n = ctr + dx * LCP + dy;
            const float4 nv0 = rgbL[n];
            const float4 nv1 = rgbL[HSTRIDE + n];
            const float spc = (float)(dx*dx + dy*dy) * (-1.f/18.f);
            const float dr0 = cv0.x-nv0.x, dg0 = cv0.y-nv0.y, db0 = cv0.z-nv0.z;
            const float dr1 = cv1.x-nv1.x, dg1 = cv1.y-nv1.y, db1 = cv1.z-nv1.z;
            const float d0 = dr0*dr0 + dg0*dg0 + db0*db0;
            const float d1 = dr1*dr1 + dg1*dg1 + db1*db1;
            const float wb0 = nv0.w * __expf(fmaf(d0, -0.5f, spc));
            const float wb1 = nv0.w * __expf(fmaf(d1, -0.5f, spc));
            half2f hw = {(_Float16)wb0, (_Float16)wb1};
            unsigned uw; __builtin_memcpy(&uw, &hw, 4);
            wbW[(t >> 1) * 200 + px * 2 + (t & 1)] = uw;
            pn0 += (float)hw.x; pn1 += (float)hw.y;
        }
        if (g == 4) wbW[24 * 200 + px * 2 + 1] = 0u;
        *(float2*)(shm + PN_OFF + (g * NPXT + px) * 8) = make_float2(pn0, pn1);
    }
    __syncthreads();

    // ---- phase 2b: inverse norms — 5-term partial reduce + separable sn ----
    float snI, bnI0, bnI1;
    if (act) {
        float bn0 = 0.f, bn1 = 0.f;
        #pragma unroll
        for (int g2 = 0; g2 < 5; ++g2) {
            const float2 p = *(const float2*)(shm + PN_OFF + (g2 * NPXT + px) * 8);
            bn0 += p.x; bn1 += p.y;
        }
        const int rg = ti0 + r, cg = tj0 + c;
        float Rr = 5.70645506f, Cc = 5.70645506f;
        Rr -= (rg < 3   ? 0.60653066f : 0.f) + (rg < 2   ? 0.80073740f : 0.f)
            + (rg < 1   ? 0.94595947f : 0.f) + (rg > 156 ? 0.60653066f : 0.f)
            + (rg > 157 ? 0.80073740f : 0.f) + (rg > 158 ? 0.94595947f : 0.f);
        Cc -= (cg < 3   ? 0.60653066f : 0.f) + (cg < 2   ? 0.80073740f : 0.f)
            + (cg < 1   ? 0.94595947f : 0.f) + (cg > 156 ? 0.60653066f : 0.f)
            + (cg > 157 ? 0.80073740f : 0.f) + (cg > 158 ? 0.94595947f : 0.f);
        snI  = fast_rcp(Rr * Cc + EPSF);
        bnI0 = fast_rcp(bn0 + EPSF);
        bnI1 = fast_rcp(bn1 + EPSF);
    }

    for (int it = 0; it < 5; ++it) {
        // drain tail publishes of this iteration (vmcnt 0) + all waves past
        // previous LDS reads (incl. 2b's partial reads) -> region A reusable
        __syncthreads();

        // interior self-write from f32 registers (overlaps tid0's poll)
        if (act) {
            const float4v sv = {smv[0], smv[1], smv[2], smv[3]};
            smF[g * HSTRIDE + ctr] = sv;
        }

        // ---- neighbor-only epoch sync (tag-encoded, poison-robust) ----
        // Bounded spin: never triggers when all blocks are live; converts a
        // would-be deadlock into a completing-but-wrong run (diagnostic).
        if (tid == 0) {
            const unsigned seq = (unsigned)(it + 1);
            if (it > 0)
                __hip_atomic_store(&bar[EPW(bid)], EPTAG | seq,
                                   __ATOMIC_RELAXED, __HIP_MEMORY_SCOPE_AGENT);
            unsigned mn;
            unsigned spins = 0;
            do {
                mn = 0xFFFFu;
                #pragma unroll
                for (int k = 0; k < 8; ++k) {
                    const unsigned w = __hip_atomic_load(&bar[EPW(nb[k])],
                                                         __ATOMIC_RELAXED, __HIP_MEMORY_SCOPE_AGENT);
                    const unsigned e = ep_decode(w);
                    mn = (e < mn) ? e : mn;
                }
                if (mn < seq) {
                    __builtin_amdgcn_s_sleep(1);
                    if (++spins > (1u << 22)) break;   // watchdog (~0.2s)
                }
            } while (mn < seq);
        }
        __syncthreads();

        // ---- stage: ring from gsm (f16 -> f32 once) ----
        const unsigned long long* gsrc = ((it & 1) ? gsmB : gsmA);
        #pragma unroll
        for (int k2 = 0; k2 < 2; ++k2) {
            const int e = tid + NTHR * k2;
            if (e < NG * NRING) {
                const int sg = e / NRING, re = e - sg * NRING;
                int hr, hc;
                if (re < 48)        { hr = re >> 4;               hc = re & 15; }
                else if (re < 96)   { hr = 13 + ((re - 48) >> 4); hc = (re - 48) & 15; }
                else                { const int t2 = re - 96; hr = 3 + t2 / 6;
                                      const int s = t2 % 6;   hc = (s < 3) ? s : s + 10; }
                const int yi = ti0 - SPAN + hr, xj = tj0 - SPAN + hc;
                float4v fv = (float4v)0.0f;
                if ((unsigned)yi < HH && (unsigned)xj < WW) {
                    const unsigned long long raw =
                        __hip_atomic_load(&gsrc[sg * NPIX + yi * WW + xj],
                                          __ATOMIC_RELAXED, __HIP_MEMORY_SCOPE_AGENT);
                    half4 hv; __builtin_memcpy(&hv, &raw, 8);
                    fv = (float4v){(float)hv[0], (float)hv[1], (float)hv[2], (float)hv[3]};
                }
                smF[sg * HSTRIDE + hr * LCP + hc] = fv;
            }
        }
        __syncthreads();

        // ---- 49 taps as 24 pairs + 1 (f32 b128 LDS reads -> v_pk_fma_f32) ----
        float4v sAv = (float4v)0.0f, b0a = (float4v)0.0f, b1a = (float4v)0.0f;
        if (act) {
            const float4v* pl = smF + g * HSTRIDE;
            #pragma unroll
            for (int i = 0; i < 24; ++i) {
                const uint2 wp = wbP[i * 100 + px];
                #pragma unroll
                for (int s = 0; s < 2; ++s) {
                    const int t = 2*i + s;
                    const int dx = t / 7 - SPAN, dy = t % 7 - SPAN;
                    half2f hw; __builtin_memcpy(&hw, s ? &wp.y : &wp.x, 4);
                    const float w0 = (float)hw.x, w1 = (float)hw.y;
                    const float4v f = pl[ctr + dx*LCP + dy];
                    sAv += WSPC[t] * f;
                    b0a += w0 * f;
                    b1a += w1 * f;
                }
            }
            {   // tap 48
                const uint2 wp = wbP[24 * 100 + px];
                half2f hw; __builtin_memcpy(&hw, &wp.x, 4);
                const float w0 = (float)hw.x, w1 = (float)hw.y;
                const float4v f = pl[ctr + SPAN*LCP + SPAN];
                sAv += WSPC[48] * f;
                b0a += w0 * f;
                b1a += w1 * f;
            }
        }

        float q0v[4], q1v[4];
        if (isdiag) {
            if (act) {
                #pragma unroll
                for (int i = 0; i < 4; ++i) {
                    const float sAn = sAv[i] * snI;
                    const float b0n = b0a[i] * bnI0;
                    const float b1x = b1a[i] * bnI1;
                    q0v[i] = uv0[i] - dsv[i]*sAn - dbv[i]*b0n;
                    q1v[i] = uv1[i] - (dsv[i] + dbv[i]) + dsv[i]*sAn + dbv[i]*b1x;
                }
            }
        } else {
            __syncthreads();   // smF dead -> region A becomes accF
            if (act) {
                #pragma unroll
                for (int i = 0; i < 4; ++i) {
                    accF[(4*g + i) * NPXT + px]      = sAv[i] * snI;
                    accF[(20 + 4*g + i) * NPXT + px] = b0a[i] * bnI0;
                    accF[(40 + 4*g + i) * NPXT + px] = b1a[i] * bnI1;
                }
            }
            __syncthreads();
            if (act) {
                float t1[4] = {0,0,0,0}, t2[4] = {0,0,0,0}, t3[4] = {0,0,0,0};
                #pragma unroll
                for (int cc = 0; cc < 20; ++cc) {
                    const float sv  = accF[cc * NPXT + px];
                    const float b0v = accF[(20 + cc) * NPXT + px];
                    const float b1v = accF[(40 + cc) * NPXT + px];
                    #pragma unroll
                    for (int i = 0; i < 4; ++i) {
                        const float* mk = Msh + (ku + i) * 48;
                        t1[i] += mk[cc] * sv;
                        t2[i] += mk[20 + cc] * b0v;
                        t3[i] += mk[20 + cc] * b1v;
                    }
                }
                #pragma unroll
                for (int i = 0; i < 4; ++i) {
                    const float rs = Msh[(ku + i) * 48 + 40];
                    q0v[i] = uv0[i] - t1[i] - t2[i];
                    q1v[i] = uv1[i] - rs + t1[i] + t3[i];
                }
            }
        }

        if (it == 4) {
            if (act) {
                #pragma unroll
                for (int i = 0; i < 4; ++i) {
                    const int ch = 4*g + i;
                    if (ch < NC) {
                        out[(size_t)gp * NC + ch]          = q0v[i];
                        out[((size_t)NPIX + gp) * NC + ch] = q1v[i];
                    }
                }
            }
        } else if (act) {
            // sm for iteration it+1: f32 in regs (interior) + f16 publish (halo)
            #pragma unroll
            for (int i = 0; i < 4; ++i) {
                smv[i] = smx0(q0v[i], q1v[i]);
                sh[i]  = (_Float16)smv[i];
            }
            unsigned long long u64; __builtin_memcpy(&u64, &sh, 8);
            unsigned long long* gdst = (((it + 1) & 1) ? gsmB : gsmA);
            __hip_atomic_store(&gdst[g * NPIX + gp], u64,
                               __ATOMIC_RELAXED, __HIP_MEMORY_SCOPE_AGENT);
        }
    }
}

extern "C" void kernel_launch(void* const* d_in, const int* in_sizes, int n_in,
                              void* d_out, int out_size, void* d_ws, size_t ws_size,
                              hipStream_t stream) {
    const float* u      = (const float*)d_in[0];
    const float* rgb    = (const float*)d_in[1];
    const float* sw     = (const float*)d_in[2];
    const float* bw     = (const float*)d_in[3];
    const float* compat = (const float*)d_in[4];
    float* out = (float*)d_out;

    unsigned long long* gsmA = (unsigned long long*)d_ws;              // 1,024,000 B
    unsigned long long* gsmB = (unsigned long long*)((char*)d_ws + 1024000);
    unsigned* bar = (unsigned*)((char*)d_ws + 2048000);                // epochs (tag-encoded)

    crf_kernel<<<dim3(WW/TC, HH/TR, 1), dim3(NTHR), 0, stream>>>(
        u, rgb, sw, bw, compat, gsmA, gsmB, bar, out);
}